// Round 12
// baseline (259.729 us; speedup 1.0000x reference)
//
#include <hip/hip_runtime.h>
#include <math.h>

#define NEG_SLOPE 0.2f
#define BN_EPS 1e-5f
#define BSH 9
#define BMASK 511
#define LOG2E 1.44269504088896f
#define BCAP 12288
#define CH_MAX 3400

typedef __attribute__((ext_vector_type(8))) short short8;
typedef __attribute__((ext_vector_type(4))) float f32x4;

__device__ __forceinline__ float wave_max64(float v) {
  #pragma unroll
  for (int o = 32; o; o >>= 1) v = fmaxf(v, __shfl_xor(v, o, 64));
  return v;
}
__device__ __forceinline__ float wave_sum64(float v) {
  #pragma unroll
  for (int o = 32; o; o >>= 1) v += __shfl_xor(v, o, 64);
  return v;
}

__device__ __forceinline__ unsigned pack2bf(float a, float b) {
  unsigned ua = __float_as_uint(a);
  unsigned ub = __float_as_uint(b);
  ua = ua + 0x7fffu + ((ua >> 16) & 1u);
  ub = ub + 0x7fffu + ((ub >> 16) & 1u);
  return (ua >> 16) | (ub & 0xffff0000u);
}
__device__ __forceinline__ float bf_lo(unsigned u) { return __uint_as_float(u << 16); }
__device__ __forceinline__ float bf_hi(unsigned u) { return __uint_as_float(u & 0xffff0000u); }

union U8 { short8 s; uint4 u; };

// ---------------------------------------------------------------------------
// prep: Mext[k][0..7]=W1[k]·att_s per head, [8..15] att_d  (PRESCALED by log2e)
//       M2ext[k][0]=W2[k]·att_s2, [1]=W2[k]·att_d2        (PRESCALED by log2e)
// ---------------------------------------------------------------------------
__global__ void prep_kernel(const float* __restrict__ W1,
                            const float* __restrict__ att_s,
                            const float* __restrict__ att_d,
                            float* __restrict__ Mext,
                            const float* __restrict__ W2,
                            const float* __restrict__ att_s2,
                            const float* __restrict__ att_d2,
                            float* __restrict__ M2ext)
{
  int k = threadIdx.x;   // 0..127
  #pragma unroll
  for (int h = 0; h < 8; ++h) {
    float s = 0.f, d = 0.f;
    #pragma unroll
    for (int c = 0; c < 16; ++c) {
      float w = W1[k * 128 + h * 16 + c];
      s += w * att_s[h * 16 + c];
      d += w * att_d[h * 16 + c];
    }
    Mext[k * 16 + h] = s * LOG2E;
    Mext[k * 16 + 8 + h] = d * LOG2E;
  }
  float s2 = 0.f, d2 = 0.f;
  #pragma unroll
  for (int c = 0; c < 40; ++c) {
    float w = W2[k * 40 + c];
    s2 += w * att_s2[c];
    d2 += w * att_d2[c];
  }
  M2ext[k * 2] = s2 * LOG2E;
  M2ext[k * 2 + 1] = d2 * LOG2E;
}

// ---------------------------------------------------------------------------
// FUSED gemm1 + scatterA. Blocks [0,G1) run the MFMA layer-1 GEMM;
// blocks [G1, G1+NBLK_A) run the fixed-capacity bucket scatter.
// Scatter is single-pass: edge chunk staged in LDS (pk + bucket id), so the
// 13.6 MB edge list is read/decoded once instead of twice.
// ---------------------------------------------------------------------------
__global__ __launch_bounds__(256) void gemm1_scatter_kernel(
    const float* __restrict__ X, const float* __restrict__ W1,
    const float* __restrict__ Wsk, const float* __restrict__ bsk,
    const float* __restrict__ Mext,
    unsigned short* __restrict__ h1f8, unsigned* __restrict__ identb,
    float* __restrict__ alpha_s, float* __restrict__ alpha_d, int N,
    const int* __restrict__ esrc, const int* __restrict__ edst,
    int* __restrict__ bcur, unsigned* __restrict__ pkbuf,
    int E, int T, int chunk, int NB, int G1)
{
  __shared__ uint4 Asm4[2048];           // 32 KB (gemm1 tile / scatter scratch)
  const int t = threadIdx.x;

  if ((int)blockIdx.x >= G1) {
    // -------------------- scatter path (single global pass) --------------------
    int* hist  = (int*)Asm4;
    int* lbase = hist + 256;
    int* lcur  = hist + 512;
    unsigned* spk = (unsigned*)(hist + 768);                 // CH_MAX entries
    unsigned char* sbk = (unsigned char*)(spk + CH_MAX);     // CH_MAX bytes
    const int bid = (int)blockIdx.x - G1;
    hist[t] = 0;
    __syncthreads();
    int s0 = bid * chunk;
    int s1 = min(s0 + chunk, T);
    for (int i = s0 + t; i < s1; i += 256) {
      int d, s;
      if (i < E) { d = edst[i]; s = esrc[i]; } else { d = s = i - E; }
      int b = d >> BSH;
      int li = i - s0;
      spk[li] = ((unsigned)(d & BMASK) << 17) | (unsigned)s;
      sbk[li] = (unsigned char)b;
      atomicAdd(&hist[b], 1);
    }
    __syncthreads();
    if (t < NB) {
      int h = hist[t];
      lbase[t] = t * BCAP + (h ? atomicAdd(&bcur[t], h) : 0);
      lcur[t] = 0;
    }
    __syncthreads();
    const int cnt2 = s1 - s0;
    for (int li = t; li < cnt2; li += 256) {
      int b = sbk[li];
      int p = lbase[b] + atomicAdd(&lcur[b], 1);
      pkbuf[p] = spk[li];
    }
    return;
  }

  // -------------------- gemm1 path --------------------
  const int l = t & 63, wave = t >> 6;
  const int lx = l & 15, ly = l >> 4;
  const int row0 = blockIdx.x * 128;
  const int wn0 = wave * 64;

  short8 b[4][4];
  short8 b4[4] = {};
  #pragma unroll
  for (int nf = 0; nf < 4; ++nf) {
    int c = wn0 + nf * 16 + lx;
    const float* bp = (c < 128) ? (W1 + c) : (Wsk + c - 128);
    #pragma unroll
    for (int kf = 0; kf < 4; ++kf) {
      int k0 = kf * 32 + ly * 8;
      U8 f;
      f.u.x = pack2bf(bp[(k0 + 0) * 128], bp[(k0 + 1) * 128]);
      f.u.y = pack2bf(bp[(k0 + 2) * 128], bp[(k0 + 3) * 128]);
      f.u.z = pack2bf(bp[(k0 + 4) * 128], bp[(k0 + 5) * 128]);
      f.u.w = pack2bf(bp[(k0 + 6) * 128], bp[(k0 + 7) * 128]);
      b[nf][kf] = f.s;
    }
  }
  if (wave == 0) {
    const float* bp = Mext + lx;
    #pragma unroll
    for (int kf = 0; kf < 4; ++kf) {
      int k0 = kf * 32 + ly * 8;
      U8 f;
      f.u.x = pack2bf(bp[(k0 + 0) * 16], bp[(k0 + 1) * 16]);
      f.u.y = pack2bf(bp[(k0 + 2) * 16], bp[(k0 + 3) * 16]);
      f.u.z = pack2bf(bp[(k0 + 4) * 16], bp[(k0 + 5) * 16]);
      f.u.w = pack2bf(bp[(k0 + 6) * 16], bp[(k0 + 7) * 16]);
      b4[kf] = f.s;
    }
  }

  {
    int rl = t >> 1;
    int half = t & 1;
    int r = row0 + rl;
    const float* xp = X + (size_t)r * 128 + half * 64;
    #pragma unroll
    for (int i = 0; i < 8; ++i) {
      float4 f0 = make_float4(0.f, 0.f, 0.f, 0.f), f1 = f0;
      if (r < N) {
        f0 = *(const float4*)(xp + i * 8);
        f1 = *(const float4*)(xp + i * 8 + 4);
      }
      uint4 u;
      u.x = pack2bf(f0.x, f0.y); u.y = pack2bf(f0.z, f0.w);
      u.z = pack2bf(f1.x, f1.y); u.w = pack2bf(f1.z, f1.w);
      int woff = (rl * 256 + half * 128 + i * 16) ^ ((rl & 7) << 4);
      *(uint4*)((char*)Asm4 + woff) = u;
    }
  }
  __syncthreads();

  float bval[4];
  if (wave >= 2) {
    #pragma unroll
    for (int nf = 0; nf < 4; ++nf) bval[nf] = bsk[(wave - 2) * 64 + nf * 16 + lx];
  }

  for (int mf = 0; mf < 8; ++mf) {
    short8 a[4];
    int rowl = mf * 16 + lx;
    #pragma unroll
    for (int kf = 0; kf < 4; ++kf)
      a[kf] = *(short8*)((char*)Asm4 + ((rowl * 256 + kf * 64 + ly * 16) ^ ((lx & 7) << 4)));

    int rbase = row0 + mf * 16 + ly * 4;

    #pragma unroll
    for (int nf = 0; nf < 4; ++nf) {
      f32x4 acc = {0.f, 0.f, 0.f, 0.f};
      #pragma unroll
      for (int kf = 0; kf < 4; ++kf)
        acc = __builtin_amdgcn_mfma_f32_16x16x32_bf16(a[kf], b[nf][kf], acc, 0, 0, 0);
      if (wave < 2) {
        int c = wn0 + nf * 16 + lx;       // even-lane pairs (c, c+1)
        #pragma unroll
        for (int reg = 0; reg < 4; ++reg) {
          float v = acc[reg];
          float vp = __shfl_xor(v, 1, 64);
          int r = rbase + reg;
          if (!(lx & 1) && r < N) {
            int u = __builtin_amdgcn_cvt_pk_fp8_f32(v, vp, 0, false);
            *(unsigned short*)((char*)h1f8 + (unsigned)r * 128u + (unsigned)c) =
                (unsigned short)u;
          }
        }
      } else {
        int c = (wave - 2) * 64 + nf * 16 + lx;
        #pragma unroll
        for (int reg = 0; reg < 4; ++reg) {
          float v = acc[reg] + bval[nf];
          float vp = __shfl_xor(v, 1, 64);
          int r = rbase + reg;
          if (!(lx & 1) && r < N)
            identb[(unsigned)r * 64u + (unsigned)(c >> 1)] = pack2bf(v, vp);
        }
      }
    }

    if (wave == 0) {
      f32x4 acc = {0.f, 0.f, 0.f, 0.f};
      #pragma unroll
      for (int kf = 0; kf < 4; ++kf)
        acc = __builtin_amdgcn_mfma_f32_16x16x32_bf16(a[kf], b4[kf], acc, 0, 0, 0);
      #pragma unroll
      for (int reg = 0; reg < 4; ++reg) {
        int r = rbase + reg;
        if (r < N) {
          if (lx < 8) alpha_s[(size_t)r * 8 + lx] = acc[reg];
          else        alpha_d[(size_t)r * 8 + (lx - 8)] = acc[reg];
        }
      }
    }
  }
}

// ---------------------------------------------------------------------------
// passB: one block per bucket (fixed base b*BCAP, count from bcur).
// Counting sort of <=512 dst values; emits starts/ends + sorted ssrc.
// ---------------------------------------------------------------------------
__global__ __launch_bounds__(256) void passB_kernel(
    const unsigned* __restrict__ pkbuf, const int* __restrict__ bcnt,
    int* __restrict__ starts, int* __restrict__ ends,
    int* __restrict__ ssrc, int N)
{
  __shared__ int cnt[512];
  __shared__ int ps[256];
  __shared__ int cur[512];
  const int t = threadIdx.x;
  const int b = blockIdx.x;
  const int bs = b * BCAP;
  const int be = bs + bcnt[b];

  cnt[t] = 0; cnt[t + 256] = 0;
  __syncthreads();
  for (int i = bs + t; i < be; i += 256)
    atomicAdd(&cnt[pkbuf[i] >> 17], 1);
  __syncthreads();

  int a = cnt[2 * t], b2 = cnt[2 * t + 1];
  ps[t] = a + b2;
  __syncthreads();
  for (int d = 1; d < 256; d <<= 1) {
    int u = (t >= d) ? ps[t - d] : 0;
    __syncthreads();
    ps[t] += u;
    __syncthreads();
  }
  int excl = ps[t] - (a + b2);
  cur[2 * t] = excl;
  cur[2 * t + 1] = excl + a;
  __syncthreads();

  const int node0 = b << BSH;
  {
    int n0 = node0 + 2 * t, n1 = node0 + 2 * t + 1;
    if (n0 < N) { starts[n0] = bs + cur[2 * t];     ends[n0] = bs + cur[2 * t] + a; }
    if (n1 < N) { starts[n1] = bs + cur[2 * t + 1]; ends[n1] = bs + cur[2 * t + 1] + b2; }
  }
  __syncthreads();

  for (int i = bs + t; i < be; i += 256) {
    unsigned pk = pkbuf[i];
    int d = pk >> 17;
    int p = atomicAdd(&cur[d], 1);
    ssrc[bs + p] = (int)(pk & 0x1FFFFu);
  }
}

// ---------------------------------------------------------------------------
// Layer-1 aggregation, two-phase, 8-deep gather pipeline (round-9 structure).
// ---------------------------------------------------------------------------
__global__ __launch_bounds__(256) void agg1_kernel(
    const int* __restrict__ starts, const int* __restrict__ ends,
    const int* __restrict__ ssrc,
    const float* __restrict__ as1, const float* __restrict__ ad1,
    const unsigned short* __restrict__ h1f8,
    const float* __restrict__ bias1, const float* __restrict__ gamma,
    const float* __restrict__ beta, const float* __restrict__ mean,
    const float* __restrict__ var,
    const unsigned* __restrict__ identb, unsigned* __restrict__ hpostb, int N)
{
  const int w = threadIdx.x >> 6, l = threadIdx.x & 63;
  const int n = blockIdx.x * 4 + w;
  if (n >= N) return;
  const int e8 = l >> 3;           // phase-1 edge slot
  const int hh = l & 7;            // phase-1 head
  const int h2_4 = (l >> 3) * 4;   // phase-2 head*4 (bpermute byte idx)
  const int c0 = l * 2;
  const unsigned l2 = (unsigned)(l * 2);
  const float adp = ad1[(unsigned)n * 8u + (unsigned)hh];
  const int jb = starts[n], je = ends[n];

  const float bb0 = bias1[c0], bb1 = bias1[c0 + 1];
  const float sc0 = gamma[c0] * rsqrtf(var[c0] + BN_EPS);
  const float sc1 = gamma[c0 + 1] * rsqrtf(var[c0 + 1] + BN_EPS);
  const float mn0 = mean[c0], mn1 = mean[c0 + 1];
  const float bt0 = beta[c0], bt1 = beta[c0 + 1];

  const char* h1c = (const char*)h1f8;

  float dsum = 0.f, a0 = 0.f, a1 = 0.f;

#define PHASE2(K, SVEC, EW) { \
    unsigned sk = (unsigned)__builtin_amdgcn_readlane(SVEC, (K) * 8); \
    float ewk = __uint_as_float( \
        __builtin_amdgcn_ds_bpermute(h2_4 + (K) * 32, __float_as_uint(EW))); \
    unsigned u8 = *(const unsigned short*)(h1c + ((size_t)sk << 7) + l2); \
    a0 += ewk * __builtin_amdgcn_cvt_f32_fp8(u8, 0); \
    a1 += ewk * __builtin_amdgcn_cvt_f32_fp8(u8, 1); }

  int j = jb;
  for (; j + 8 <= je; j += 8) {
    int svec = ssrc[j + e8];
    float e = as1[(unsigned)svec * 8u + (unsigned)hh] + adp;
    e = fmaxf(e, NEG_SLOPE * e);
    float ew = exp2f(e);
    dsum += ew;
    PHASE2(0, svec, ew) PHASE2(1, svec, ew) PHASE2(2, svec, ew) PHASE2(3, svec, ew)
    PHASE2(4, svec, ew) PHASE2(5, svec, ew) PHASE2(6, svec, ew) PHASE2(7, svec, ew)
  }
  int rem = je - j;
  if (rem > 0) {
    int jj = j + (e8 < rem ? e8 : 0);
    int svec = ssrc[jj];
    float e = as1[(unsigned)svec * 8u + (unsigned)hh] + adp;
    e = fmaxf(e, NEG_SLOPE * e);
    float ew = (e8 < rem) ? exp2f(e) : 0.f;
    dsum += ew;
    for (int k = 0; k < rem; ++k) {
      unsigned sk = (unsigned)__builtin_amdgcn_readlane(svec, k * 8);
      float ewk = __uint_as_float(
          __builtin_amdgcn_ds_bpermute(h2_4 + (k << 5), __float_as_uint(ew)));
      unsigned u8 = *(const unsigned short*)(h1c + ((size_t)sk << 7) + l2);
      a0 += ewk * __builtin_amdgcn_cvt_f32_fp8(u8, 0);
      a1 += ewk * __builtin_amdgcn_cvt_f32_fp8(u8, 1);
    }
  }
#undef PHASE2

  dsum += __shfl_xor(dsum, 8, 64);
  dsum += __shfl_xor(dsum, 16, 64);
  dsum += __shfl_xor(dsum, 32, 64);
  float denom = __uint_as_float(
      __builtin_amdgcn_ds_bpermute(h2_4, __float_as_uint(dsum)));

  float inv = 1.f / (denom + 1e-16f);
  unsigned uid = identb[(unsigned)n * 64u + (unsigned)l];
  float o0 = a0 * inv + bb0;
  float o1 = a1 * inv + bb1;
  o0 = (o0 - mn0) * sc0 + bt0;
  o1 = (o1 - mn1) * sc1 + bt1;
  o0 = o0 > 0.f ? o0 : expm1f(o0);
  o1 = o1 > 0.f ? o1 : expm1f(o1);
  o0 += bf_lo(uid); o1 += bf_hi(uid);
  hpostb[(unsigned)n * 64u + (unsigned)l] = pack2bf(o0, o1);
}

// ---------------------------------------------------------------------------
// MFMA GEMM2, LDS-free. h2 split: h2a [N][16 uints] (64 B, ch 0..31) and
// h2b2 [N][4 uints] (16 B, ch 32..39).
// ---------------------------------------------------------------------------
__global__ __launch_bounds__(256) void gemm2_kernel(
    const unsigned* __restrict__ hpostb, const float* __restrict__ W2,
    const float* __restrict__ M2ext,
    unsigned* __restrict__ h2a, unsigned* __restrict__ h2b2,
    float* __restrict__ as2, float* __restrict__ ad2, int N)
{
  const int t = threadIdx.x;
  const int l = t & 63, wave = t >> 6;
  const int lx = l & 15, ly = l >> 4;
  const int row0 = blockIdx.x * 128;

  short8 b[3][4];
  short8 b4[4];
  {
    #pragma unroll
    for (int nf = 0; nf < 3; ++nf) {
      int col = nf * 16 + lx;
      bool v = col < 40;
      const float* bp = W2 + (v ? col : 0);
      #pragma unroll
      for (int kf = 0; kf < 4; ++kf) {
        int k0 = kf * 32 + ly * 8;
        U8 f;
        if (v) {
          f.u.x = pack2bf(bp[(k0 + 0) * 40], bp[(k0 + 1) * 40]);
          f.u.y = pack2bf(bp[(k0 + 2) * 40], bp[(k0 + 3) * 40]);
          f.u.z = pack2bf(bp[(k0 + 4) * 40], bp[(k0 + 5) * 40]);
          f.u.w = pack2bf(bp[(k0 + 6) * 40], bp[(k0 + 7) * 40]);
        } else {
          f.u = make_uint4(0, 0, 0, 0);
        }
        b[nf][kf] = f.s;
      }
    }
    bool va = lx < 2;
    const float* bp = M2ext + (va ? lx : 0);
    #pragma unroll
    for (int kf = 0; kf < 4; ++kf) {
      int k0 = kf * 32 + ly * 8;
      U8 f;
      if (va) {
        f.u.x = pack2bf(bp[(k0 + 0) * 2], bp[(k0 + 1) * 2]);
        f.u.y = pack2bf(bp[(k0 + 2) * 2], bp[(k0 + 3) * 2]);
        f.u.z = pack2bf(bp[(k0 + 4) * 2], bp[(k0 + 5) * 2]);
        f.u.w = pack2bf(bp[(k0 + 6) * 2], bp[(k0 + 7) * 2]);
      } else {
        f.u = make_uint4(0, 0, 0, 0);
      }
      b4[kf] = f.s;
    }
  }

  #pragma unroll
  for (int i2 = 0; i2 < 2; ++i2) {
    int mf = wave * 2 + i2;
    int arow = row0 + mf * 16 + lx;
    short8 a[4];
    #pragma unroll
    for (int kf = 0; kf < 4; ++kf) {
      U8 f;
      f.u = make_uint4(0, 0, 0, 0);
      if (arow < N)
        f.u = *(const uint4*)(hpostb + (unsigned)arow * 64u + (unsigned)(kf * 16 + ly * 4));
      a[kf] = f.s;
    }

    int rbase = row0 + mf * 16 + ly * 4;

    #pragma unroll
    for (int nf = 0; nf < 3; ++nf) {
      f32x4 acc = {0.f, 0.f, 0.f, 0.f};
      #pragma unroll
      for (int kf = 0; kf < 4; ++kf)
        acc = __builtin_amdgcn_mfma_f32_16x16x32_bf16(a[kf], b[nf][kf], acc, 0, 0, 0);
      int c = nf * 16 + lx;
      int cp = c >> 1;
      #pragma unroll
      for (int reg = 0; reg < 4; ++reg) {
        float v = acc[reg];
        float vp = __shfl_xor(v, 1, 64);
        int r = rbase + reg;
        if (r < N && c < 40 && !(lx & 1)) {
          unsigned pk = pack2bf(v, vp);
          if (cp < 16) h2a[((unsigned)r << 4) + (unsigned)cp] = pk;
          else         h2b2[((unsigned)r << 2) + (unsigned)(cp - 16)] = pk;
        }
      }
    }
    {
      f32x4 acc = {0.f, 0.f, 0.f, 0.f};
      #pragma unroll
      for (int kf = 0; kf < 4; ++kf)
        acc = __builtin_amdgcn_mfma_f32_16x16x32_bf16(a[kf], b4[kf], acc, 0, 0, 0);
      #pragma unroll
      for (int reg = 0; reg < 4; ++reg) {
        int r = rbase + reg;
        if (r < N) {
          if (lx == 0) as2[r] = acc[reg];
          else if (lx == 1) ad2[r] = acc[reg];
        }
      }
    }
  }
}

// ---------------------------------------------------------------------------
// Layer-2 aggregation, two-phase (agg1 recipe, heads=1 so readlane replaces
// bpermute): phase 1 lanes 0..15 compute 16 edge weights; phase 2 per edge
// broadcasts s and ew to SGPRs -> saddr+const-voffset gathers, scalar-operand
// FMAs. Fused bias2 + log_softmax epilogue.
// ---------------------------------------------------------------------------
__global__ __launch_bounds__(256) void agg2_kernel(
    const int* __restrict__ starts, const int* __restrict__ ends,
    const int* __restrict__ ssrc,
    const float* __restrict__ as2, const float* __restrict__ ad2,
    const unsigned* __restrict__ h2a, const unsigned* __restrict__ h2b2,
    const float* __restrict__ bias2,
    float* __restrict__ outp, int N)
{
  const int w = threadIdx.x >> 6, l = threadIdx.x & 63;
  const int n = blockIdx.x * 4 + w;
  if (n >= N) return;
  const int cl = l < 20 ? l : 0;            // channel pair 0..19
  const unsigned ca = (unsigned)((l & 15) * 4);  // voffset into h2a row
  const unsigned cb = (unsigned)((l & 3) * 4);   // voffset into h2b2 row
  const bool useA = (cl < 16);
  const float ad = ad2[n];                  // prescaled
  const int jb = starts[n], je = ends[n];

  const char* h2ac = (const char*)h2a;
  const char* h2bc = (const char*)h2b2;

  float dsum = 0.f, a0 = 0.f, a1 = 0.f;

#define E2PHASE2(K, SVEC, EW) { \
    unsigned sk = (unsigned)__builtin_amdgcn_readlane(SVEC, (K)); \
    float ewk = __uint_as_float(__builtin_amdgcn_readlane(__float_as_uint(EW), (K))); \
    unsigned ua = *(const unsigned*)(h2ac + ((size_t)sk << 6) + ca); \
    unsigned ub = *(const unsigned*)(h2bc + ((size_t)sk << 4) + cb); \
    unsigned u = useA ? ua : ub; \
    a0 += ewk * bf_lo(u); \
    a1 += ewk * bf_hi(u); }

  int j = jb;
  for (; j + 16 <= je; j += 16) {
    int svec = ssrc[j + (l & 15)];
    float e = as2[(unsigned)svec] + ad;
    e = fmaxf(e, NEG_SLOPE * e);
    float ew = (l < 16) ? exp2f(e) : 0.f;
    dsum += ew;
    E2PHASE2(0, svec, ew)  E2PHASE2(1, svec, ew)  E2PHASE2(2, svec, ew)  E2PHASE2(3, svec, ew)
    E2PHASE2(4, svec, ew)  E2PHASE2(5, svec, ew)  E2PHASE2(6, svec, ew)  E2PHASE2(7, svec, ew)
    E2PHASE2(8, svec, ew)  E2PHASE2(9, svec, ew)  E2PHASE2(10, svec, ew) E2PHASE2(11, svec, ew)
    E2PHASE2(12, svec, ew) E2PHASE2(13, svec, ew) E2PHASE2(14, svec, ew) E2PHASE2(15, svec, ew)
  }
  int rem = je - j;
  if (rem > 0) {
    int svec = ssrc[j + ((l & 15) < rem ? (l & 15) : 0)];
    float e = as2[(unsigned)svec] + ad;
    e = fmaxf(e, NEG_SLOPE * e);
    float ew = (l < rem) ? exp2f(e) : 0.f;
    dsum += ew;
    for (int k = 0; k < rem; ++k) {
      unsigned sk = (unsigned)__builtin_amdgcn_readlane(svec, k);
      float ewk = __uint_as_float(__builtin_amdgcn_readlane(__float_as_uint(ew), k));
      unsigned ua = *(const unsigned*)(h2ac + ((size_t)sk << 6) + ca);
      unsigned ub = *(const unsigned*)(h2bc + ((size_t)sk << 4) + cb);
      unsigned u = useA ? ua : ub;
      a0 += ewk * bf_lo(u);
      a1 += ewk * bf_hi(u);
    }
  }
#undef E2PHASE2

  float denom = wave_sum64(dsum);
  float inv = 1.f / (denom + 1e-16f);
  float o0 = a0 * inv + bias2[2 * cl];
  float o1 = a1 * inv + bias2[2 * cl + 1];

  float mx = wave_max64(l < 20 ? fmaxf(o0, o1) : -3.4e38f);
  float se = wave_sum64(l < 20 ? __expf(o0 - mx) + __expf(o1 - mx) : 0.f);
  float ls = logf(se);
  if (l < 20)
    *(float2*)&outp[(size_t)n * 40 + 2 * l] = make_float2(o0 - mx - ls, o1 - mx - ls);
}

// ---------------------------------------------------------------------------
extern "C" void kernel_launch(void* const* d_in, const int* in_sizes, int n_in,
                              void* d_out, int out_size, void* d_ws, size_t ws_size,
                              hipStream_t stream)
{
  const float* x        = (const float*)d_in[0];
  const int*   ei       = (const int*)d_in[1];
  const float* W1       = (const float*)d_in[2];
  const float* att_src1 = (const float*)d_in[3];
  const float* att_dst1 = (const float*)d_in[4];
  const float* bias1    = (const float*)d_in[5];
  const float* bn_gamma = (const float*)d_in[6];
  const float* bn_beta  = (const float*)d_in[7];
  const float* bn_mean  = (const float*)d_in[8];
  const float* bn_var   = (const float*)d_in[9];
  const float* W2       = (const float*)d_in[10];
  const float* att_src2 = (const float*)d_in[11];
  const float* att_dst2 = (const float*)d_in[12];
  const float* bias2    = (const float*)d_in[13];
  const float* W_skip   = (const float*)d_in[14];
  const float* b_skip   = (const float*)d_in[15];

  const int N = in_sizes[0] / 128;
  const int E = in_sizes[1] / 2;
  const int T = E + N;
  const int NB = (N + BMASK) >> BSH;   // 196

  char* p = (char*)d_ws;
  auto alloc = [&](size_t bytes) { char* q = p; p += (bytes + 255) & ~255ull; return q; };
  unsigned short* h1f8 = (unsigned short*)alloc((size_t)N * 128);   // fp8 [N][128]
  unsigned* hpostb = (unsigned*)alloc((size_t)N * 64 * 4);          // bf16 [N][128]
  unsigned* identb = (unsigned*)alloc((size_t)N * 64 * 4);          // bf16 [N][128]
  float* as1     = (float*)alloc((size_t)N * 8 * 4);
  float* ad1     = (float*)alloc((size_t)N * 8 * 4);
  float* Mext    = (float*)alloc(128 * 16 * 4);
  float* M2ext   = (float*)alloc(128 * 2 * 4);
  int*   starts  = (int*)alloc((size_t)N * 4);
  int*   ends    = (int*)alloc((size_t)N * 4);
  unsigned* pkbuf= (unsigned*)alloc((size_t)NB * BCAP * 4);
  int*   ssrc    = (int*)alloc((size_t)NB * BCAP * 4);
  int*   bcur    = (int*)alloc((size_t)NB * 4);
  // layer-2 reuse of dead layer-1 buffers (h1f8/as1/ad1 dead after agg1)
  unsigned* h2a  = (unsigned*)h1f8;                 // [N][16] uints = N*64 B
  unsigned* h2b2 = (unsigned*)((char*)h1f8 + (size_t)N * 64);  // [N][4] uints
  float* as2 = as1;
  float* ad2 = ad1;

  const int* ei_src = ei;
  const int* ei_dst = ei + E;

  hipMemsetAsync(bcur, 0, (size_t)NB * 4, stream);

  prep_kernel<<<1, 128, 0, stream>>>(W1, att_src1, att_dst1, Mext,
                                     W2, att_src2, att_dst2, M2ext);

  const int G1 = (N + 127) / 128;
  int NBLK_A = (T + CH_MAX - 1) / CH_MAX;
  if (NBLK_A < 512) NBLK_A = 512;
  const int chunk = (T + NBLK_A - 1) / NBLK_A;
  gemm1_scatter_kernel<<<G1 + NBLK_A, 256, 0, stream>>>(
      x, W1, W_skip, b_skip, Mext, h1f8, identb, as1, ad1, N,
      ei_src, ei_dst, bcur, pkbuf, E, T, chunk, NB, G1);

  passB_kernel<<<NB, 256, 0, stream>>>(pkbuf, bcur, starts, ends, ssrc, N);

  agg1_kernel<<<(N + 3) / 4, 256, 0, stream>>>(starts, ends, ssrc, as1, ad1, h1f8,
                                               bias1, bn_gamma, bn_beta, bn_mean, bn_var,
                                               identb, hpostb, N);
  gemm2_kernel<<<(N + 127) / 128, 256, 0, stream>>>(hpostb, W2, M2ext,
                                                    h2a, h2b2, as2, ad2, N);
  agg2_kernel<<<(N + 3) / 4, 256, 0, stream>>>(starts, ends, ssrc, as2, ad2,
                                               h2a, h2b2, bias2,
                                               (float*)d_out, N);
}

// Round 13
// 243.986 us; speedup vs baseline: 1.0645x; 1.0645x over previous
//
#include <hip/hip_runtime.h>
#include <math.h>

#define NEG_SLOPE 0.2f
#define BN_EPS 1e-5f
#define BSH 9
#define BMASK 511
#define LOG2E 1.44269504088896f
#define BCAP 12288
#define CH_MAX 3400

typedef __attribute__((ext_vector_type(8))) short short8;
typedef __attribute__((ext_vector_type(4))) float f32x4;

__device__ __forceinline__ float wave_max64(float v) {
  #pragma unroll
  for (int o = 32; o; o >>= 1) v = fmaxf(v, __shfl_xor(v, o, 64));
  return v;
}
__device__ __forceinline__ float wave_sum64(float v) {
  #pragma unroll
  for (int o = 32; o; o >>= 1) v += __shfl_xor(v, o, 64);
  return v;
}

__device__ __forceinline__ unsigned pack2bf(float a, float b) {
  unsigned ua = __float_as_uint(a);
  unsigned ub = __float_as_uint(b);
  ua = ua + 0x7fffu + ((ua >> 16) & 1u);
  ub = ub + 0x7fffu + ((ub >> 16) & 1u);
  return (ua >> 16) | (ub & 0xffff0000u);
}
__device__ __forceinline__ float bf_lo(unsigned u) { return __uint_as_float(u << 16); }
__device__ __forceinline__ float bf_hi(unsigned u) { return __uint_as_float(u & 0xffff0000u); }

union U8 { short8 s; uint4 u; };

// ---------------------------------------------------------------------------
// prep: Mext[k][0..7]=W1[k]·att_s per head, [8..15] att_d  (PRESCALED by log2e)
//       M2ext[k][0]=W2[k]·att_s2, [1]=W2[k]·att_d2        (PRESCALED by log2e)
// Also zeroes bcur (folds the memset launch).
// ---------------------------------------------------------------------------
__global__ void prep_kernel(const float* __restrict__ W1,
                            const float* __restrict__ att_s,
                            const float* __restrict__ att_d,
                            float* __restrict__ Mext,
                            const float* __restrict__ W2,
                            const float* __restrict__ att_s2,
                            const float* __restrict__ att_d2,
                            float* __restrict__ M2ext,
                            int* __restrict__ bcur, int NB)
{
  int k = threadIdx.x;   // 0..255
  if (k < NB) bcur[k] = 0;
  if (k >= 128) return;
  #pragma unroll
  for (int h = 0; h < 8; ++h) {
    float s = 0.f, d = 0.f;
    #pragma unroll
    for (int c = 0; c < 16; ++c) {
      float w = W1[k * 128 + h * 16 + c];
      s += w * att_s[h * 16 + c];
      d += w * att_d[h * 16 + c];
    }
    Mext[k * 16 + h] = s * LOG2E;
    Mext[k * 16 + 8 + h] = d * LOG2E;
  }
  float s2 = 0.f, d2 = 0.f;
  #pragma unroll
  for (int c = 0; c < 40; ++c) {
    float w = W2[k * 40 + c];
    s2 += w * att_s2[c];
    d2 += w * att_d2[c];
  }
  M2ext[k * 2] = s2 * LOG2E;
  M2ext[k * 2 + 1] = d2 * LOG2E;
}

// ---------------------------------------------------------------------------
// FUSED gemm1 + scatterA. Blocks [0,G1) run the MFMA layer-1 GEMM;
// blocks [G1, G1+NBLK_A) run the fixed-capacity bucket scatter.
// Scatter is single-pass: edge chunk staged in LDS (pk + bucket id).
// ---------------------------------------------------------------------------
__global__ __launch_bounds__(256) void gemm1_scatter_kernel(
    const float* __restrict__ X, const float* __restrict__ W1,
    const float* __restrict__ Wsk, const float* __restrict__ bsk,
    const float* __restrict__ Mext,
    unsigned short* __restrict__ h1f8, unsigned* __restrict__ identb,
    float* __restrict__ alpha_s, float* __restrict__ alpha_d, int N,
    const int* __restrict__ esrc, const int* __restrict__ edst,
    int* __restrict__ bcur, unsigned* __restrict__ pkbuf,
    int E, int T, int chunk, int NB, int G1)
{
  __shared__ uint4 Asm4[2048];           // 32 KB (gemm1 tile / scatter scratch)
  const int t = threadIdx.x;

  if ((int)blockIdx.x >= G1) {
    // -------------------- scatter path (single global pass) ----------------
    int* hist  = (int*)Asm4;
    int* lbase = hist + 256;
    int* lcur  = hist + 512;
    unsigned* spk = (unsigned*)(hist + 768);                 // CH_MAX entries
    unsigned char* sbk = (unsigned char*)(spk + CH_MAX);     // CH_MAX bytes
    const int bid = (int)blockIdx.x - G1;
    hist[t] = 0;
    __syncthreads();
    int s0 = bid * chunk;
    int s1 = min(s0 + chunk, T);
    for (int i = s0 + t; i < s1; i += 256) {
      int d, s;
      if (i < E) { d = edst[i]; s = esrc[i]; } else { d = s = i - E; }
      int b = d >> BSH;
      int li = i - s0;
      spk[li] = ((unsigned)(d & BMASK) << 17) | (unsigned)s;
      sbk[li] = (unsigned char)b;
      atomicAdd(&hist[b], 1);
    }
    __syncthreads();
    if (t < NB) {
      int h = hist[t];
      lbase[t] = t * BCAP + (h ? atomicAdd(&bcur[t], h) : 0);
      lcur[t] = 0;
    }
    __syncthreads();
    const int cnt2 = s1 - s0;
    for (int li = t; li < cnt2; li += 256) {
      int b = sbk[li];
      int p = lbase[b] + atomicAdd(&lcur[b], 1);
      pkbuf[p] = spk[li];
    }
    return;
  }

  // -------------------- gemm1 path --------------------
  const int l = t & 63, wave = t >> 6;
  const int lx = l & 15, ly = l >> 4;
  const int row0 = blockIdx.x * 128;
  const int wn0 = wave * 64;

  short8 b[4][4];
  short8 b4[4] = {};
  #pragma unroll
  for (int nf = 0; nf < 4; ++nf) {
    int c = wn0 + nf * 16 + lx;
    const float* bp = (c < 128) ? (W1 + c) : (Wsk + c - 128);
    #pragma unroll
    for (int kf = 0; kf < 4; ++kf) {
      int k0 = kf * 32 + ly * 8;
      U8 f;
      f.u.x = pack2bf(bp[(k0 + 0) * 128], bp[(k0 + 1) * 128]);
      f.u.y = pack2bf(bp[(k0 + 2) * 128], bp[(k0 + 3) * 128]);
      f.u.z = pack2bf(bp[(k0 + 4) * 128], bp[(k0 + 5) * 128]);
      f.u.w = pack2bf(bp[(k0 + 6) * 128], bp[(k0 + 7) * 128]);
      b[nf][kf] = f.s;
    }
  }
  if (wave == 0) {
    const float* bp = Mext + lx;
    #pragma unroll
    for (int kf = 0; kf < 4; ++kf) {
      int k0 = kf * 32 + ly * 8;
      U8 f;
      f.u.x = pack2bf(bp[(k0 + 0) * 16], bp[(k0 + 1) * 16]);
      f.u.y = pack2bf(bp[(k0 + 2) * 16], bp[(k0 + 3) * 16]);
      f.u.z = pack2bf(bp[(k0 + 4) * 16], bp[(k0 + 5) * 16]);
      f.u.w = pack2bf(bp[(k0 + 6) * 16], bp[(k0 + 7) * 16]);
      b4[kf] = f.s;
    }
  }

  {
    int rl = t >> 1;
    int half = t & 1;
    int r = row0 + rl;
    const float* xp = X + (size_t)r * 128 + half * 64;
    #pragma unroll
    for (int i = 0; i < 8; ++i) {
      float4 f0 = make_float4(0.f, 0.f, 0.f, 0.f), f1 = f0;
      if (r < N) {
        f0 = *(const float4*)(xp + i * 8);
        f1 = *(const float4*)(xp + i * 8 + 4);
      }
      uint4 u;
      u.x = pack2bf(f0.x, f0.y); u.y = pack2bf(f0.z, f0.w);
      u.z = pack2bf(f1.x, f1.y); u.w = pack2bf(f1.z, f1.w);
      int woff = (rl * 256 + half * 128 + i * 16) ^ ((rl & 7) << 4);
      *(uint4*)((char*)Asm4 + woff) = u;
    }
  }
  __syncthreads();

  float bval[4];
  if (wave >= 2) {
    #pragma unroll
    for (int nf = 0; nf < 4; ++nf) bval[nf] = bsk[(wave - 2) * 64 + nf * 16 + lx];
  }

  for (int mf = 0; mf < 8; ++mf) {
    short8 a[4];
    int rowl = mf * 16 + lx;
    #pragma unroll
    for (int kf = 0; kf < 4; ++kf)
      a[kf] = *(short8*)((char*)Asm4 + ((rowl * 256 + kf * 64 + ly * 16) ^ ((lx & 7) << 4)));

    int rbase = row0 + mf * 16 + ly * 4;

    #pragma unroll
    for (int nf = 0; nf < 4; ++nf) {
      f32x4 acc = {0.f, 0.f, 0.f, 0.f};
      #pragma unroll
      for (int kf = 0; kf < 4; ++kf)
        acc = __builtin_amdgcn_mfma_f32_16x16x32_bf16(a[kf], b[nf][kf], acc, 0, 0, 0);
      if (wave < 2) {
        int c = wn0 + nf * 16 + lx;       // even-lane pairs (c, c+1)
        #pragma unroll
        for (int reg = 0; reg < 4; ++reg) {
          float v = acc[reg];
          float vp = __shfl_xor(v, 1, 64);
          int r = rbase + reg;
          if (!(lx & 1) && r < N) {
            int u = __builtin_amdgcn_cvt_pk_fp8_f32(v, vp, 0, false);
            *(unsigned short*)((char*)h1f8 + (unsigned)r * 128u + (unsigned)c) =
                (unsigned short)u;
          }
        }
      } else {
        int c = (wave - 2) * 64 + nf * 16 + lx;
        #pragma unroll
        for (int reg = 0; reg < 4; ++reg) {
          float v = acc[reg] + bval[nf];
          float vp = __shfl_xor(v, 1, 64);
          int r = rbase + reg;
          if (!(lx & 1) && r < N)
            identb[(unsigned)r * 64u + (unsigned)(c >> 1)] = pack2bf(v, vp);
        }
      }
    }

    if (wave == 0) {
      f32x4 acc = {0.f, 0.f, 0.f, 0.f};
      #pragma unroll
      for (int kf = 0; kf < 4; ++kf)
        acc = __builtin_amdgcn_mfma_f32_16x16x32_bf16(a[kf], b4[kf], acc, 0, 0, 0);
      #pragma unroll
      for (int reg = 0; reg < 4; ++reg) {
        int r = rbase + reg;
        if (r < N) {
          if (lx < 8) alpha_s[(size_t)r * 8 + lx] = acc[reg];
          else        alpha_d[(size_t)r * 8 + (lx - 8)] = acc[reg];
        }
      }
    }
  }
}

// ---------------------------------------------------------------------------
// passB: one block per bucket (fixed base b*BCAP, count from bcur).
// Counting sort of <=512 dst values; emits starts/ends + sorted ssrc.
// ---------------------------------------------------------------------------
__global__ __launch_bounds__(256) void passB_kernel(
    const unsigned* __restrict__ pkbuf, const int* __restrict__ bcnt,
    int* __restrict__ starts, int* __restrict__ ends,
    int* __restrict__ ssrc, int N)
{
  __shared__ int cnt[512];
  __shared__ int ps[256];
  __shared__ int cur[512];
  const int t = threadIdx.x;
  const int b = blockIdx.x;
  const int bs = b * BCAP;
  const int be = bs + bcnt[b];

  cnt[t] = 0; cnt[t + 256] = 0;
  __syncthreads();
  for (int i = bs + t; i < be; i += 256)
    atomicAdd(&cnt[pkbuf[i] >> 17], 1);
  __syncthreads();

  int a = cnt[2 * t], b2 = cnt[2 * t + 1];
  ps[t] = a + b2;
  __syncthreads();
  for (int d = 1; d < 256; d <<= 1) {
    int u = (t >= d) ? ps[t - d] : 0;
    __syncthreads();
    ps[t] += u;
    __syncthreads();
  }
  int excl = ps[t] - (a + b2);
  cur[2 * t] = excl;
  cur[2 * t + 1] = excl + a;
  __syncthreads();

  const int node0 = b << BSH;
  {
    int n0 = node0 + 2 * t, n1 = node0 + 2 * t + 1;
    if (n0 < N) { starts[n0] = bs + cur[2 * t];     ends[n0] = bs + cur[2 * t] + a; }
    if (n1 < N) { starts[n1] = bs + cur[2 * t + 1]; ends[n1] = bs + cur[2 * t + 1] + b2; }
  }
  __syncthreads();

  for (int i = bs + t; i < be; i += 256) {
    unsigned pk = pkbuf[i];
    int d = pk >> 17;
    int p = atomicAdd(&cur[d], 1);
    ssrc[bs + p] = (int)(pk & 0x1FFFFu);
  }
}

// ---------------------------------------------------------------------------
// Layer-1 aggregation, two-phase, 8-deep gather pipeline (round-9 structure).
// ---------------------------------------------------------------------------
__global__ __launch_bounds__(256) void agg1_kernel(
    const int* __restrict__ starts, const int* __restrict__ ends,
    const int* __restrict__ ssrc,
    const float* __restrict__ as1, const float* __restrict__ ad1,
    const unsigned short* __restrict__ h1f8,
    const float* __restrict__ bias1, const float* __restrict__ gamma,
    const float* __restrict__ beta, const float* __restrict__ mean,
    const float* __restrict__ var,
    const unsigned* __restrict__ identb, unsigned* __restrict__ hpostb, int N)
{
  const int w = threadIdx.x >> 6, l = threadIdx.x & 63;
  const int n = blockIdx.x * 4 + w;
  if (n >= N) return;
  const int e8 = l >> 3;           // phase-1 edge slot
  const int hh = l & 7;            // phase-1 head
  const int h2_4 = (l >> 3) * 4;   // phase-2 head*4 (bpermute byte idx)
  const int c0 = l * 2;
  const unsigned l2 = (unsigned)(l * 2);
  const float adp = ad1[(unsigned)n * 8u + (unsigned)hh];
  const int jb = starts[n], je = ends[n];

  const float bb0 = bias1[c0], bb1 = bias1[c0 + 1];
  const float sc0 = gamma[c0] * rsqrtf(var[c0] + BN_EPS);
  const float sc1 = gamma[c0 + 1] * rsqrtf(var[c0 + 1] + BN_EPS);
  const float mn0 = mean[c0], mn1 = mean[c0 + 1];
  const float bt0 = beta[c0], bt1 = beta[c0 + 1];

  const char* h1c = (const char*)h1f8;

  float dsum = 0.f, a0 = 0.f, a1 = 0.f;

#define PHASE2(K, SVEC, EW) { \
    unsigned sk = (unsigned)__builtin_amdgcn_readlane(SVEC, (K) * 8); \
    float ewk = __uint_as_float( \
        __builtin_amdgcn_ds_bpermute(h2_4 + (K) * 32, __float_as_uint(EW))); \
    unsigned u8 = *(const unsigned short*)(h1c + ((size_t)sk << 7) + l2); \
    a0 += ewk * __builtin_amdgcn_cvt_f32_fp8(u8, 0); \
    a1 += ewk * __builtin_amdgcn_cvt_f32_fp8(u8, 1); }

  int j = jb;
  for (; j + 8 <= je; j += 8) {
    int svec = ssrc[j + e8];
    float e = as1[(unsigned)svec * 8u + (unsigned)hh] + adp;
    e = fmaxf(e, NEG_SLOPE * e);
    float ew = exp2f(e);
    dsum += ew;
    PHASE2(0, svec, ew) PHASE2(1, svec, ew) PHASE2(2, svec, ew) PHASE2(3, svec, ew)
    PHASE2(4, svec, ew) PHASE2(5, svec, ew) PHASE2(6, svec, ew) PHASE2(7, svec, ew)
  }
  int rem = je - j;
  if (rem > 0) {
    int jj = j + (e8 < rem ? e8 : 0);
    int svec = ssrc[jj];
    float e = as1[(unsigned)svec * 8u + (unsigned)hh] + adp;
    e = fmaxf(e, NEG_SLOPE * e);
    float ew = (e8 < rem) ? exp2f(e) : 0.f;
    dsum += ew;
    for (int k = 0; k < rem; ++k) {
      unsigned sk = (unsigned)__builtin_amdgcn_readlane(svec, k * 8);
      float ewk = __uint_as_float(
          __builtin_amdgcn_ds_bpermute(h2_4 + (k << 5), __float_as_uint(ew)));
      unsigned u8 = *(const unsigned short*)(h1c + ((size_t)sk << 7) + l2);
      a0 += ewk * __builtin_amdgcn_cvt_f32_fp8(u8, 0);
      a1 += ewk * __builtin_amdgcn_cvt_f32_fp8(u8, 1);
    }
  }
#undef PHASE2

  dsum += __shfl_xor(dsum, 8, 64);
  dsum += __shfl_xor(dsum, 16, 64);
  dsum += __shfl_xor(dsum, 32, 64);
  float denom = __uint_as_float(
      __builtin_amdgcn_ds_bpermute(h2_4, __float_as_uint(dsum)));

  float inv = 1.f / (denom + 1e-16f);
  unsigned uid = identb[(unsigned)n * 64u + (unsigned)l];
  float o0 = a0 * inv + bb0;
  float o1 = a1 * inv + bb1;
  o0 = (o0 - mn0) * sc0 + bt0;
  o1 = (o1 - mn1) * sc1 + bt1;
  o0 = o0 > 0.f ? o0 : expm1f(o0);
  o1 = o1 > 0.f ? o1 : expm1f(o1);
  o0 += bf_lo(uid); o1 += bf_hi(uid);
  hpostb[(unsigned)n * 64u + (unsigned)l] = pack2bf(o0, o1);
}

// ---------------------------------------------------------------------------
// MFMA GEMM2, LDS-free. h2 split: h2a [N][16 uints] (64 B, ch 0..31) and
// h2b2 [N][4 uints] (16 B, ch 32..39).
// ---------------------------------------------------------------------------
__global__ __launch_bounds__(256) void gemm2_kernel(
    const unsigned* __restrict__ hpostb, const float* __restrict__ W2,
    const float* __restrict__ M2ext,
    unsigned* __restrict__ h2a, unsigned* __restrict__ h2b2,
    float* __restrict__ as2, float* __restrict__ ad2, int N)
{
  const int t = threadIdx.x;
  const int l = t & 63, wave = t >> 6;
  const int lx = l & 15, ly = l >> 4;
  const int row0 = blockIdx.x * 128;

  short8 b[3][4];
  short8 b4[4];
  {
    #pragma unroll
    for (int nf = 0; nf < 3; ++nf) {
      int col = nf * 16 + lx;
      bool v = col < 40;
      const float* bp = W2 + (v ? col : 0);
      #pragma unroll
      for (int kf = 0; kf < 4; ++kf) {
        int k0 = kf * 32 + ly * 8;
        U8 f;
        if (v) {
          f.u.x = pack2bf(bp[(k0 + 0) * 40], bp[(k0 + 1) * 40]);
          f.u.y = pack2bf(bp[(k0 + 2) * 40], bp[(k0 + 3) * 40]);
          f.u.z = pack2bf(bp[(k0 + 4) * 40], bp[(k0 + 5) * 40]);
          f.u.w = pack2bf(bp[(k0 + 6) * 40], bp[(k0 + 7) * 40]);
        } else {
          f.u = make_uint4(0, 0, 0, 0);
        }
        b[nf][kf] = f.s;
      }
    }
    bool va = lx < 2;
    const float* bp = M2ext + (va ? lx : 0);
    #pragma unroll
    for (int kf = 0; kf < 4; ++kf) {
      int k0 = kf * 32 + ly * 8;
      U8 f;
      if (va) {
        f.u.x = pack2bf(bp[(k0 + 0) * 2], bp[(k0 + 1) * 2]);
        f.u.y = pack2bf(bp[(k0 + 2) * 2], bp[(k0 + 3) * 2]);
        f.u.z = pack2bf(bp[(k0 + 4) * 2], bp[(k0 + 5) * 2]);
        f.u.w = pack2bf(bp[(k0 + 6) * 2], bp[(k0 + 7) * 2]);
      } else {
        f.u = make_uint4(0, 0, 0, 0);
      }
      b4[kf] = f.s;
    }
  }

  #pragma unroll
  for (int i2 = 0; i2 < 2; ++i2) {
    int mf = wave * 2 + i2;
    int arow = row0 + mf * 16 + lx;
    short8 a[4];
    #pragma unroll
    for (int kf = 0; kf < 4; ++kf) {
      U8 f;
      f.u = make_uint4(0, 0, 0, 0);
      if (arow < N)
        f.u = *(const uint4*)(hpostb + (unsigned)arow * 64u + (unsigned)(kf * 16 + ly * 4));
      a[kf] = f.s;
    }

    int rbase = row0 + mf * 16 + ly * 4;

    #pragma unroll
    for (int nf = 0; nf < 3; ++nf) {
      f32x4 acc = {0.f, 0.f, 0.f, 0.f};
      #pragma unroll
      for (int kf = 0; kf < 4; ++kf)
        acc = __builtin_amdgcn_mfma_f32_16x16x32_bf16(a[kf], b[nf][kf], acc, 0, 0, 0);
      int c = nf * 16 + lx;
      int cp = c >> 1;
      #pragma unroll
      for (int reg = 0; reg < 4; ++reg) {
        float v = acc[reg];
        float vp = __shfl_xor(v, 1, 64);
        int r = rbase + reg;
        if (r < N && c < 40 && !(lx & 1)) {
          unsigned pk = pack2bf(v, vp);
          if (cp < 16) h2a[((unsigned)r << 4) + (unsigned)cp] = pk;
          else         h2b2[((unsigned)r << 2) + (unsigned)(cp - 16)] = pk;
        }
      }
    }
    {
      f32x4 acc = {0.f, 0.f, 0.f, 0.f};
      #pragma unroll
      for (int kf = 0; kf < 4; ++kf)
        acc = __builtin_amdgcn_mfma_f32_16x16x32_bf16(a[kf], b4[kf], acc, 0, 0, 0);
      #pragma unroll
      for (int reg = 0; reg < 4; ++reg) {
        int r = rbase + reg;
        if (r < N) {
          if (lx == 0) as2[r] = acc[reg];
          else if (lx == 1) ad2[r] = acc[reg];
        }
      }
    }
  }
}

// ---------------------------------------------------------------------------
// Layer-2 aggregation + bias2 + fused log_softmax. 3 edge-groups of 20 lanes,
// x3 unrolled; split h2 buffers (per-lane constant base+shift); exp2 weights.
// (Round-11 structure — the two-phase readlane variant issued 6x more VMEM.)
// ---------------------------------------------------------------------------
__global__ __launch_bounds__(256) void agg2_kernel(
    const int* __restrict__ starts, const int* __restrict__ ends,
    const int* __restrict__ ssrc,
    const float* __restrict__ as2, const float* __restrict__ ad2,
    const unsigned* __restrict__ h2a, const unsigned* __restrict__ h2b2,
    const float* __restrict__ bias2,
    float* __restrict__ outp, int N)
{
  const int w = threadIdx.x >> 6, l = threadIdx.x & 63;
  const int n = blockIdx.x * 4 + w;
  if (n >= N) return;
  const int g = l / 20;            // 0,1,2 (3 for idle lanes)
  const int cl = l - g * 20;       // channel pair 0..19
  const bool act = l < 60;
  const float ad = ad2[n];         // prescaled
  const int jb = starts[n], je = ends[n];

  // per-lane gather base: cl<16 -> h2a row (64 B, shift 6), else h2b2 (16 B, shift 4)
  const char* hbase = (cl < 16) ? ((const char*)h2a + (unsigned)cl * 4u)
                                : ((const char*)h2b2 + (unsigned)(cl - 16) * 4u);
  const unsigned hshift = (cl < 16) ? 6u : 4u;
  const char* as2c = (const char*)as2;

  float denom = 0.f, a0 = 0.f, a1 = 0.f;

#define EDGE2(JJ, GUARD) { \
    bool v = act && (GUARD); \
    unsigned s = v ? (unsigned)ssrc[JJ] : 0u; \
    float e = *(const float*)(as2c + (s << 2)) + ad; \
    e = fmaxf(e, NEG_SLOPE * e); \
    float ex = v ? exp2f(e) : 0.f; \
    unsigned u = *(const unsigned*)(hbase + ((size_t)s << hshift)); \
    denom += ex; \
    a0 += ex * bf_lo(u); \
    a1 += ex * bf_hi(u); }

  int j = jb;
  for (; j + 9 <= je; j += 9) {
    EDGE2(j + g, true)
    EDGE2(j + 3 + g, true)
    EDGE2(j + 6 + g, true)
  }
  for (; j < je; j += 3) {
    EDGE2(j + g, (j + g) < je)
  }
#undef EDGE2

  a0 += __shfl(a0, l + 20, 64) + __shfl(a0, l + 40, 64);
  a1 += __shfl(a1, l + 20, 64) + __shfl(a1, l + 40, 64);
  denom += __shfl(denom, l + 20, 64) + __shfl(denom, l + 40, 64);

  const int lc = l < 20 ? l : 0;
  float inv = 1.f / (denom + 1e-16f);
  float o0 = a0 * inv + bias2[2 * lc];
  float o1 = a1 * inv + bias2[2 * lc + 1];

  float mx = wave_max64(l < 20 ? fmaxf(o0, o1) : -3.4e38f);
  float se = wave_sum64(l < 20 ? __expf(o0 - mx) + __expf(o1 - mx) : 0.f);
  float ls = logf(se);
  if (l < 20)
    *(float2*)&outp[(size_t)n * 40 + 2 * l] = make_float2(o0 - mx - ls, o1 - mx - ls);
}

// ---------------------------------------------------------------------------
extern "C" void kernel_launch(void* const* d_in, const int* in_sizes, int n_in,
                              void* d_out, int out_size, void* d_ws, size_t ws_size,
                              hipStream_t stream)
{
  const float* x        = (const float*)d_in[0];
  const int*   ei       = (const int*)d_in[1];
  const float* W1       = (const float*)d_in[2];
  const float* att_src1 = (const float*)d_in[3];
  const float* att_dst1 = (const float*)d_in[4];
  const float* bias1    = (const float*)d_in[5];
  const float* bn_gamma = (const float*)d_in[6];
  const float* bn_beta  = (const float*)d_in[7];
  const float* bn_mean  = (const float*)d_in[8];
  const float* bn_var   = (const float*)d_in[9];
  const float* W2       = (const float*)d_in[10];
  const float* att_src2 = (const float*)d_in[11];
  const float* att_dst2 = (const float*)d_in[12];
  const float* bias2    = (const float*)d_in[13];
  const float* W_skip   = (const float*)d_in[14];
  const float* b_skip   = (const float*)d_in[15];

  const int N = in_sizes[0] / 128;
  const int E = in_sizes[1] / 2;
  const int T = E + N;
  const int NB = (N + BMASK) >> BSH;   // 196

  char* p = (char*)d_ws;
  auto alloc = [&](size_t bytes) { char* q = p; p += (bytes + 255) & ~255ull; return q; };
  unsigned short* h1f8 = (unsigned short*)alloc((size_t)N * 128);   // fp8 [N][128]
  unsigned* hpostb = (unsigned*)alloc((size_t)N * 64 * 4);          // bf16 [N][128]
  unsigned* identb = (unsigned*)alloc((size_t)N * 64 * 4);          // bf16 [N][128]
  float* as1     = (float*)alloc((size_t)N * 8 * 4);
  float* ad1     = (float*)alloc((size_t)N * 8 * 4);
  float* Mext    = (float*)alloc(128 * 16 * 4);
  float* M2ext   = (float*)alloc(128 * 2 * 4);
  int*   starts  = (int*)alloc((size_t)N * 4);
  int*   ends    = (int*)alloc((size_t)N * 4);
  unsigned* pkbuf= (unsigned*)alloc((size_t)NB * BCAP * 4);
  int*   ssrc    = (int*)alloc((size_t)NB * BCAP * 4);
  int*   bcur    = (int*)alloc((size_t)NB * 4);
  // layer-2 reuse of dead layer-1 buffers (h1f8/as1/ad1 dead after agg1)
  unsigned* h2a  = (unsigned*)h1f8;                 // [N][16] uints = N*64 B
  unsigned* h2b2 = (unsigned*)((char*)h1f8 + (size_t)N * 64);  // [N][4] uints
  float* as2 = as1;
  float* ad2 = ad1;

  const int* ei_src = ei;
  const int* ei_dst = ei + E;

  prep_kernel<<<1, 256, 0, stream>>>(W1, att_src1, att_dst1, Mext,
                                     W2, att_src2, att_dst2, M2ext,
                                     bcur, NB);

  const int G1 = (N + 127) / 128;
  int NBLK_A = (T + CH_MAX - 1) / CH_MAX;
  if (NBLK_A < 512) NBLK_A = 512;
  const int chunk = (T + NBLK_A - 1) / NBLK_A;
  gemm1_scatter_kernel<<<G1 + NBLK_A, 256, 0, stream>>>(
      x, W1, W_skip, b_skip, Mext, h1f8, identb, as1, ad1, N,
      ei_src, ei_dst, bcur, pkbuf, E, T, chunk, NB, G1);

  passB_kernel<<<NB, 256, 0, stream>>>(pkbuf, bcur, starts, ends, ssrc, N);

  agg1_kernel<<<(N + 3) / 4, 256, 0, stream>>>(starts, ends, ssrc, as1, ad1, h1f8,
                                               bias1, bn_gamma, bn_beta, bn_mean, bn_var,
                                               identb, hpostb, N);
  gemm2_kernel<<<(N + 127) / 128, 256, 0, stream>>>(hpostb, W2, M2ext,
                                                    h2a, h2b2, as2, ad2, N);
  agg2_kernel<<<(N + 3) / 4, 256, 0, stream>>>(starts, ends, ssrc, as2, ad2,
                                               h2a, h2b2, bias2,
                                               (float*)d_out, N);
}

// Round 14
// 231.855 us; speedup vs baseline: 1.1202x; 1.0523x over previous
//
#include <hip/hip_runtime.h>
#include <math.h>

#define NEG_SLOPE 0.2f
#define BN_EPS 1e-5f
#define BSH 9
#define BMASK 511
#define LOG2E 1.44269504088896f
#define BCAP 12288
#define CH_MAX 3400

typedef __attribute__((ext_vector_type(8))) short short8;
typedef __attribute__((ext_vector_type(4))) float f32x4;

__device__ __forceinline__ float wave_max64(float v) {
  #pragma unroll
  for (int o = 32; o; o >>= 1) v = fmaxf(v, __shfl_xor(v, o, 64));
  return v;
}
__device__ __forceinline__ float wave_sum64(float v) {
  #pragma unroll
  for (int o = 32; o; o >>= 1) v += __shfl_xor(v, o, 64);
  return v;
}

__device__ __forceinline__ unsigned pack2bf(float a, float b) {
  unsigned ua = __float_as_uint(a);
  unsigned ub = __float_as_uint(b);
  ua = ua + 0x7fffu + ((ua >> 16) & 1u);
  ub = ub + 0x7fffu + ((ub >> 16) & 1u);
  return (ua >> 16) | (ub & 0xffff0000u);
}
__device__ __forceinline__ float bf_lo(unsigned u) { return __uint_as_float(u << 16); }
__device__ __forceinline__ float bf_hi(unsigned u) { return __uint_as_float(u & 0xffff0000u); }

union U8 { short8 s; uint4 u; };

// ---------------------------------------------------------------------------
// prep: Mext[k][0..7]=W1[k]·att_s per head, [8..15] att_d  (PRESCALED by log2e)
//       M2ext[k][0]=W2[k]·att_s2, [1]=W2[k]·att_d2        (PRESCALED by log2e)
// Also zeroes bcur (folds the memset launch).
// ---------------------------------------------------------------------------
__global__ void prep_kernel(const float* __restrict__ W1,
                            const float* __restrict__ att_s,
                            const float* __restrict__ att_d,
                            float* __restrict__ Mext,
                            const float* __restrict__ W2,
                            const float* __restrict__ att_s2,
                            const float* __restrict__ att_d2,
                            float* __restrict__ M2ext,
                            int* __restrict__ bcur, int NB)
{
  int k = threadIdx.x;   // 0..255
  if (k < NB) bcur[k] = 0;
  if (k >= 128) return;
  #pragma unroll
  for (int h = 0; h < 8; ++h) {
    float s = 0.f, d = 0.f;
    #pragma unroll
    for (int c = 0; c < 16; ++c) {
      float w = W1[k * 128 + h * 16 + c];
      s += w * att_s[h * 16 + c];
      d += w * att_d[h * 16 + c];
    }
    Mext[k * 16 + h] = s * LOG2E;
    Mext[k * 16 + 8 + h] = d * LOG2E;
  }
  float s2 = 0.f, d2 = 0.f;
  #pragma unroll
  for (int c = 0; c < 40; ++c) {
    float w = W2[k * 40 + c];
    s2 += w * att_s2[c];
    d2 += w * att_d2[c];
  }
  M2ext[k * 2] = s2 * LOG2E;
  M2ext[k * 2 + 1] = d2 * LOG2E;
}

// ---------------------------------------------------------------------------
// FUSED gemm1 + scatterA. Blocks [0,G1) run the MFMA layer-1 GEMM;
// blocks [G1, G1+NBLK_A) run the fixed-capacity bucket scatter.
// Scatter is single-pass: edge chunk staged in LDS (pk + bucket id).
// ---------------------------------------------------------------------------
__global__ __launch_bounds__(256) void gemm1_scatter_kernel(
    const float* __restrict__ X, const float* __restrict__ W1,
    const float* __restrict__ Wsk, const float* __restrict__ bsk,
    const float* __restrict__ Mext,
    unsigned short* __restrict__ h1f8, unsigned* __restrict__ identb,
    float* __restrict__ alpha_s, float* __restrict__ alpha_d, int N,
    const int* __restrict__ esrc, const int* __restrict__ edst,
    int* __restrict__ bcur, unsigned* __restrict__ pkbuf,
    int E, int T, int chunk, int NB, int G1)
{
  __shared__ uint4 Asm4[2048];           // 32 KB (gemm1 tile / scatter scratch)
  const int t = threadIdx.x;

  if ((int)blockIdx.x >= G1) {
    // -------------------- scatter path (single global pass) ----------------
    int* hist  = (int*)Asm4;
    int* lbase = hist + 256;
    int* lcur  = hist + 512;
    unsigned* spk = (unsigned*)(hist + 768);                 // CH_MAX entries
    unsigned char* sbk = (unsigned char*)(spk + CH_MAX);     // CH_MAX bytes
    const int bid = (int)blockIdx.x - G1;
    hist[t] = 0;
    __syncthreads();
    int s0 = bid * chunk;
    int s1 = min(s0 + chunk, T);
    for (int i = s0 + t; i < s1; i += 256) {
      int d, s;
      if (i < E) { d = edst[i]; s = esrc[i]; } else { d = s = i - E; }
      int b = d >> BSH;
      int li = i - s0;
      spk[li] = ((unsigned)(d & BMASK) << 17) | (unsigned)s;
      sbk[li] = (unsigned char)b;
      atomicAdd(&hist[b], 1);
    }
    __syncthreads();
    if (t < NB) {
      int h = hist[t];
      lbase[t] = t * BCAP + (h ? atomicAdd(&bcur[t], h) : 0);
      lcur[t] = 0;
    }
    __syncthreads();
    const int cnt2 = s1 - s0;
    for (int li = t; li < cnt2; li += 256) {
      int b = sbk[li];
      int p = lbase[b] + atomicAdd(&lcur[b], 1);
      pkbuf[p] = spk[li];
    }
    return;
  }

  // -------------------- gemm1 path --------------------
  const int l = t & 63, wave = t >> 6;
  const int lx = l & 15, ly = l >> 4;
  const int row0 = blockIdx.x * 128;
  const int wn0 = wave * 64;

  short8 b[4][4];
  short8 b4[4] = {};
  #pragma unroll
  for (int nf = 0; nf < 4; ++nf) {
    int c = wn0 + nf * 16 + lx;
    const float* bp = (c < 128) ? (W1 + c) : (Wsk + c - 128);
    #pragma unroll
    for (int kf = 0; kf < 4; ++kf) {
      int k0 = kf * 32 + ly * 8;
      U8 f;
      f.u.x = pack2bf(bp[(k0 + 0) * 128], bp[(k0 + 1) * 128]);
      f.u.y = pack2bf(bp[(k0 + 2) * 128], bp[(k0 + 3) * 128]);
      f.u.z = pack2bf(bp[(k0 + 4) * 128], bp[(k0 + 5) * 128]);
      f.u.w = pack2bf(bp[(k0 + 6) * 128], bp[(k0 + 7) * 128]);
      b[nf][kf] = f.s;
    }
  }
  if (wave == 0) {
    const float* bp = Mext + lx;
    #pragma unroll
    for (int kf = 0; kf < 4; ++kf) {
      int k0 = kf * 32 + ly * 8;
      U8 f;
      f.u.x = pack2bf(bp[(k0 + 0) * 16], bp[(k0 + 1) * 16]);
      f.u.y = pack2bf(bp[(k0 + 2) * 16], bp[(k0 + 3) * 16]);
      f.u.z = pack2bf(bp[(k0 + 4) * 16], bp[(k0 + 5) * 16]);
      f.u.w = pack2bf(bp[(k0 + 6) * 16], bp[(k0 + 7) * 16]);
      b4[kf] = f.s;
    }
  }

  {
    int rl = t >> 1;
    int half = t & 1;
    int r = row0 + rl;
    const float* xp = X + (size_t)r * 128 + half * 64;
    #pragma unroll
    for (int i = 0; i < 8; ++i) {
      float4 f0 = make_float4(0.f, 0.f, 0.f, 0.f), f1 = f0;
      if (r < N) {
        f0 = *(const float4*)(xp + i * 8);
        f1 = *(const float4*)(xp + i * 8 + 4);
      }
      uint4 u;
      u.x = pack2bf(f0.x, f0.y); u.y = pack2bf(f0.z, f0.w);
      u.z = pack2bf(f1.x, f1.y); u.w = pack2bf(f1.z, f1.w);
      int woff = (rl * 256 + half * 128 + i * 16) ^ ((rl & 7) << 4);
      *(uint4*)((char*)Asm4 + woff) = u;
    }
  }
  __syncthreads();

  float bval[4];
  if (wave >= 2) {
    #pragma unroll
    for (int nf = 0; nf < 4; ++nf) bval[nf] = bsk[(wave - 2) * 64 + nf * 16 + lx];
  }

  for (int mf = 0; mf < 8; ++mf) {
    short8 a[4];
    int rowl = mf * 16 + lx;
    #pragma unroll
    for (int kf = 0; kf < 4; ++kf)
      a[kf] = *(short8*)((char*)Asm4 + ((rowl * 256 + kf * 64 + ly * 16) ^ ((lx & 7) << 4)));

    int rbase = row0 + mf * 16 + ly * 4;

    #pragma unroll
    for (int nf = 0; nf < 4; ++nf) {
      f32x4 acc = {0.f, 0.f, 0.f, 0.f};
      #pragma unroll
      for (int kf = 0; kf < 4; ++kf)
        acc = __builtin_amdgcn_mfma_f32_16x16x32_bf16(a[kf], b[nf][kf], acc, 0, 0, 0);
      if (wave < 2) {
        int c = wn0 + nf * 16 + lx;       // even-lane pairs (c, c+1)
        #pragma unroll
        for (int reg = 0; reg < 4; ++reg) {
          float v = acc[reg];
          float vp = __shfl_xor(v, 1, 64);
          int r = rbase + reg;
          if (!(lx & 1) && r < N) {
            int u = __builtin_amdgcn_cvt_pk_fp8_f32(v, vp, 0, false);
            *(unsigned short*)((char*)h1f8 + (unsigned)r * 128u + (unsigned)c) =
                (unsigned short)u;
          }
        }
      } else {
        int c = (wave - 2) * 64 + nf * 16 + lx;
        #pragma unroll
        for (int reg = 0; reg < 4; ++reg) {
          float v = acc[reg] + bval[nf];
          float vp = __shfl_xor(v, 1, 64);
          int r = rbase + reg;
          if (!(lx & 1) && r < N)
            identb[(unsigned)r * 64u + (unsigned)(c >> 1)] = pack2bf(v, vp);
        }
      }
    }

    if (wave == 0) {
      f32x4 acc = {0.f, 0.f, 0.f, 0.f};
      #pragma unroll
      for (int kf = 0; kf < 4; ++kf)
        acc = __builtin_amdgcn_mfma_f32_16x16x32_bf16(a[kf], b4[kf], acc, 0, 0, 0);
      #pragma unroll
      for (int reg = 0; reg < 4; ++reg) {
        int r = rbase + reg;
        if (r < N) {
          if (lx < 8) alpha_s[(size_t)r * 8 + lx] = acc[reg];
          else        alpha_d[(size_t)r * 8 + (lx - 8)] = acc[reg];
        }
      }
    }
  }
}

// ---------------------------------------------------------------------------
// passB: one block per bucket (fixed base b*BCAP, count from bcur).
// ---------------------------------------------------------------------------
__global__ __launch_bounds__(256) void passB_kernel(
    const unsigned* __restrict__ pkbuf, const int* __restrict__ bcnt,
    int* __restrict__ starts, int* __restrict__ ends,
    int* __restrict__ ssrc, int N)
{
  __shared__ int cnt[512];
  __shared__ int ps[256];
  __shared__ int cur[512];
  const int t = threadIdx.x;
  const int b = blockIdx.x;
  const int bs = b * BCAP;
  const int be = bs + bcnt[b];

  cnt[t] = 0; cnt[t + 256] = 0;
  __syncthreads();
  for (int i = bs + t; i < be; i += 256)
    atomicAdd(&cnt[pkbuf[i] >> 17], 1);
  __syncthreads();

  int a = cnt[2 * t], b2 = cnt[2 * t + 1];
  ps[t] = a + b2;
  __syncthreads();
  for (int d = 1; d < 256; d <<= 1) {
    int u = (t >= d) ? ps[t - d] : 0;
    __syncthreads();
    ps[t] += u;
    __syncthreads();
  }
  int excl = ps[t] - (a + b2);
  cur[2 * t] = excl;
  cur[2 * t + 1] = excl + a;
  __syncthreads();

  const int node0 = b << BSH;
  {
    int n0 = node0 + 2 * t, n1 = node0 + 2 * t + 1;
    if (n0 < N) { starts[n0] = bs + cur[2 * t];     ends[n0] = bs + cur[2 * t] + a; }
    if (n1 < N) { starts[n1] = bs + cur[2 * t + 1]; ends[n1] = bs + cur[2 * t + 1] + b2; }
  }
  __syncthreads();

  for (int i = bs + t; i < be; i += 256) {
    unsigned pk = pkbuf[i];
    int d = pk >> 17;
    int p = atomicAdd(&cur[d], 1);
    ssrc[bs + p] = (int)(pk & 0x1FFFFu);
  }
}

// ---------------------------------------------------------------------------
// Layer-1 aggregation, two-phase, 8-deep gather pipeline (round-9 structure).
// ---------------------------------------------------------------------------
__global__ __launch_bounds__(256) void agg1_kernel(
    const int* __restrict__ starts, const int* __restrict__ ends,
    const int* __restrict__ ssrc,
    const float* __restrict__ as1, const float* __restrict__ ad1,
    const unsigned short* __restrict__ h1f8,
    const float* __restrict__ bias1, const float* __restrict__ gamma,
    const float* __restrict__ beta, const float* __restrict__ mean,
    const float* __restrict__ var,
    const unsigned* __restrict__ identb, unsigned* __restrict__ hpostb, int N)
{
  const int w = threadIdx.x >> 6, l = threadIdx.x & 63;
  const int n = blockIdx.x * 4 + w;
  if (n >= N) return;
  const int e8 = l >> 3;           // phase-1 edge slot
  const int hh = l & 7;            // phase-1 head
  const int h2_4 = (l >> 3) * 4;   // phase-2 head*4 (bpermute byte idx)
  const int c0 = l * 2;
  const unsigned l2 = (unsigned)(l * 2);
  const float adp = ad1[(unsigned)n * 8u + (unsigned)hh];
  const int jb = starts[n], je = ends[n];

  const float bb0 = bias1[c0], bb1 = bias1[c0 + 1];
  const float sc0 = gamma[c0] * rsqrtf(var[c0] + BN_EPS);
  const float sc1 = gamma[c0 + 1] * rsqrtf(var[c0 + 1] + BN_EPS);
  const float mn0 = mean[c0], mn1 = mean[c0 + 1];
  const float bt0 = beta[c0], bt1 = beta[c0 + 1];

  const char* h1c = (const char*)h1f8;

  float dsum = 0.f, a0 = 0.f, a1 = 0.f;

#define PHASE2(K, SVEC, EW) { \
    unsigned sk = (unsigned)__builtin_amdgcn_readlane(SVEC, (K) * 8); \
    float ewk = __uint_as_float( \
        __builtin_amdgcn_ds_bpermute(h2_4 + (K) * 32, __float_as_uint(EW))); \
    unsigned u8 = *(const unsigned short*)(h1c + ((size_t)sk << 7) + l2); \
    a0 += ewk * __builtin_amdgcn_cvt_f32_fp8(u8, 0); \
    a1 += ewk * __builtin_amdgcn_cvt_f32_fp8(u8, 1); }

  int j = jb;
  for (; j + 8 <= je; j += 8) {
    int svec = ssrc[j + e8];
    float e = as1[(unsigned)svec * 8u + (unsigned)hh] + adp;
    e = fmaxf(e, NEG_SLOPE * e);
    float ew = exp2f(e);
    dsum += ew;
    PHASE2(0, svec, ew) PHASE2(1, svec, ew) PHASE2(2, svec, ew) PHASE2(3, svec, ew)
    PHASE2(4, svec, ew) PHASE2(5, svec, ew) PHASE2(6, svec, ew) PHASE2(7, svec, ew)
  }
  int rem = je - j;
  if (rem > 0) {
    int jj = j + (e8 < rem ? e8 : 0);
    int svec = ssrc[jj];
    float e = as1[(unsigned)svec * 8u + (unsigned)hh] + adp;
    e = fmaxf(e, NEG_SLOPE * e);
    float ew = (e8 < rem) ? exp2f(e) : 0.f;
    dsum += ew;
    for (int k = 0; k < rem; ++k) {
      unsigned sk = (unsigned)__builtin_amdgcn_readlane(svec, k * 8);
      float ewk = __uint_as_float(
          __builtin_amdgcn_ds_bpermute(h2_4 + (k << 5), __float_as_uint(ew)));
      unsigned u8 = *(const unsigned short*)(h1c + ((size_t)sk << 7) + l2);
      a0 += ewk * __builtin_amdgcn_cvt_f32_fp8(u8, 0);
      a1 += ewk * __builtin_amdgcn_cvt_f32_fp8(u8, 1);
    }
  }
#undef PHASE2

  dsum += __shfl_xor(dsum, 8, 64);
  dsum += __shfl_xor(dsum, 16, 64);
  dsum += __shfl_xor(dsum, 32, 64);
  float denom = __uint_as_float(
      __builtin_amdgcn_ds_bpermute(h2_4, __float_as_uint(dsum)));

  float inv = 1.f / (denom + 1e-16f);
  unsigned uid = identb[(unsigned)n * 64u + (unsigned)l];
  float o0 = a0 * inv + bb0;
  float o1 = a1 * inv + bb1;
  o0 = (o0 - mn0) * sc0 + bt0;
  o1 = (o1 - mn1) * sc1 + bt1;
  o0 = o0 > 0.f ? o0 : expm1f(o0);
  o1 = o1 > 0.f ? o1 : expm1f(o1);
  o0 += bf_lo(uid); o1 += bf_hi(uid);
  hpostb[(unsigned)n * 64u + (unsigned)l] = pack2bf(o0, o1);
}

// ---------------------------------------------------------------------------
// MFMA GEMM2, LDS-free. h2 output in FP8 e4m3, split:
// h2a8 [N][8 uints] (32 B, ch 0..31, 3.2 MB -> fits per-XCD L2) and
// h2b28 [N][2 uints] (8 B, ch 32..39, 0.8 MB -> L2-hot).
// ---------------------------------------------------------------------------
__global__ __launch_bounds__(256) void gemm2_kernel(
    const unsigned* __restrict__ hpostb, const float* __restrict__ W2,
    const float* __restrict__ M2ext,
    unsigned* __restrict__ h2a8, unsigned* __restrict__ h2b28,
    float* __restrict__ as2, float* __restrict__ ad2, int N)
{
  const int t = threadIdx.x;
  const int l = t & 63, wave = t >> 6;
  const int lx = l & 15, ly = l >> 4;
  const int row0 = blockIdx.x * 128;

  short8 b[3][4];
  short8 b4[4];
  {
    #pragma unroll
    for (int nf = 0; nf < 3; ++nf) {
      int col = nf * 16 + lx;
      bool v = col < 40;
      const float* bp = W2 + (v ? col : 0);
      #pragma unroll
      for (int kf = 0; kf < 4; ++kf) {
        int k0 = kf * 32 + ly * 8;
        U8 f;
        if (v) {
          f.u.x = pack2bf(bp[(k0 + 0) * 40], bp[(k0 + 1) * 40]);
          f.u.y = pack2bf(bp[(k0 + 2) * 40], bp[(k0 + 3) * 40]);
          f.u.z = pack2bf(bp[(k0 + 4) * 40], bp[(k0 + 5) * 40]);
          f.u.w = pack2bf(bp[(k0 + 6) * 40], bp[(k0 + 7) * 40]);
        } else {
          f.u = make_uint4(0, 0, 0, 0);
        }
        b[nf][kf] = f.s;
      }
    }
    bool va = lx < 2;
    const float* bp = M2ext + (va ? lx : 0);
    #pragma unroll
    for (int kf = 0; kf < 4; ++kf) {
      int k0 = kf * 32 + ly * 8;
      U8 f;
      if (va) {
        f.u.x = pack2bf(bp[(k0 + 0) * 2], bp[(k0 + 1) * 2]);
        f.u.y = pack2bf(bp[(k0 + 2) * 2], bp[(k0 + 3) * 2]);
        f.u.z = pack2bf(bp[(k0 + 4) * 2], bp[(k0 + 5) * 2]);
        f.u.w = pack2bf(bp[(k0 + 6) * 2], bp[(k0 + 7) * 2]);
      } else {
        f.u = make_uint4(0, 0, 0, 0);
      }
      b4[kf] = f.s;
    }
  }

  #pragma unroll
  for (int i2 = 0; i2 < 2; ++i2) {
    int mf = wave * 2 + i2;
    int arow = row0 + mf * 16 + lx;
    short8 a[4];
    #pragma unroll
    for (int kf = 0; kf < 4; ++kf) {
      U8 f;
      f.u = make_uint4(0, 0, 0, 0);
      if (arow < N)
        f.u = *(const uint4*)(hpostb + (unsigned)arow * 64u + (unsigned)(kf * 16 + ly * 4));
      a[kf] = f.s;
    }

    int rbase = row0 + mf * 16 + ly * 4;

    #pragma unroll
    for (int nf = 0; nf < 3; ++nf) {
      f32x4 acc = {0.f, 0.f, 0.f, 0.f};
      #pragma unroll
      for (int kf = 0; kf < 4; ++kf)
        acc = __builtin_amdgcn_mfma_f32_16x16x32_bf16(a[kf], b[nf][kf], acc, 0, 0, 0);
      int c = nf * 16 + lx;
      #pragma unroll
      for (int reg = 0; reg < 4; ++reg) {
        float v = acc[reg];
        float v1 = __shfl_xor(v, 1, 64);
        float v2 = __shfl_xor(v, 2, 64);
        float v3 = __shfl_xor(v1, 2, 64);
        int r = rbase + reg;
        if (r < N && c < 40 && !(lx & 3)) {
          int u = __builtin_amdgcn_cvt_pk_fp8_f32(v, v1, 0, false);
          u = __builtin_amdgcn_cvt_pk_fp8_f32(v2, v3, u, true);
          int c4 = c >> 2;
          if (c < 32) h2a8[((unsigned)r << 3) + (unsigned)c4] = (unsigned)u;
          else        h2b28[((unsigned)r << 1) + (unsigned)(c4 - 8)] = (unsigned)u;
        }
      }
    }
    {
      f32x4 acc = {0.f, 0.f, 0.f, 0.f};
      #pragma unroll
      for (int kf = 0; kf < 4; ++kf)
        acc = __builtin_amdgcn_mfma_f32_16x16x32_bf16(a[kf], b4[kf], acc, 0, 0, 0);
      #pragma unroll
      for (int reg = 0; reg < 4; ++reg) {
        int r = rbase + reg;
        if (r < N) {
          if (lx == 0) as2[r] = acc[reg];
          else if (lx == 1) ad2[r] = acc[reg];
        }
      }
    }
  }
}

// ---------------------------------------------------------------------------
// Layer-2 aggregation + bias2 + fused log_softmax. FP8 h2 gather:
// 6 edge-groups of 10 lanes (lane = 1 dword = 4 fp8 channels), x2 unrolled.
// Group combine via 3 shfl; lanes 0..9 write float4 outputs.
// ---------------------------------------------------------------------------
__global__ __launch_bounds__(256) void agg2_kernel(
    const int* __restrict__ starts, const int* __restrict__ ends,
    const int* __restrict__ ssrc,
    const float* __restrict__ as2, const float* __restrict__ ad2,
    const unsigned* __restrict__ h2a8, const unsigned* __restrict__ h2b28,
    const float* __restrict__ bias2,
    float* __restrict__ outp, int N)
{
  const int w = threadIdx.x >> 6, l = threadIdx.x & 63;
  const int n = blockIdx.x * 4 + w;
  if (n >= N) return;
  const int g = l / 10;            // 0..5 (6 for idle lanes 60-63)
  const int q = l - g * 10;        // dword index 0..9
  const bool act = l < 60;
  const float ad = ad2[n];         // prescaled
  const int jb = starts[n], je = ends[n];

  // per-lane gather base: q<8 -> h2a8 row (32 B, shift 5), else h2b28 (8 B, shift 3)
  const char* hbase = (q < 8) ? ((const char*)h2a8 + (unsigned)q * 4u)
                              : ((const char*)h2b28 + (unsigned)(q - 8) * 4u);
  const unsigned hshift = (q < 8) ? 5u : 3u;
  const char* as2c = (const char*)as2;

  float dsum = 0.f, a0 = 0.f, a1 = 0.f, a2 = 0.f, a3 = 0.f;

#define EDGE2(JJ, GUARD) { \
    bool v_ = act && (GUARD); \
    unsigned s = v_ ? (unsigned)ssrc[JJ] : 0u; \
    float e = *(const float*)(as2c + (s << 2)) + ad; \
    e = fmaxf(e, NEG_SLOPE * e); \
    float ex = v_ ? exp2f(e) : 0.f; \
    unsigned u = *(const unsigned*)(hbase + ((size_t)s << hshift)); \
    dsum += ex; \
    a0 += ex * __builtin_amdgcn_cvt_f32_fp8(u, 0); \
    a1 += ex * __builtin_amdgcn_cvt_f32_fp8(u, 1); \
    a2 += ex * __builtin_amdgcn_cvt_f32_fp8(u, 2); \
    a3 += ex * __builtin_amdgcn_cvt_f32_fp8(u, 3); }

  int j = jb;
  for (; j + 12 <= je; j += 12) {
    EDGE2(j + g, true)
    EDGE2(j + 6 + g, true)
  }
  for (; j < je; j += 6) {
    EDGE2(j + g, (j + g) < je)
  }
#undef EDGE2

  // combine the 6 groups (stride 10) into lanes 0..9
#define COMB(A) { \
    float t_ = A + __shfl(A, l + 30, 64); \
    A = t_ + __shfl(t_, l + 10, 64) + __shfl(t_, l + 20, 64); }
  COMB(a0) COMB(a1) COMB(a2) COMB(a3) COMB(dsum)
#undef COMB

  float inv = 1.f / (dsum + 1e-16f);
  float o0 = a0 * inv + bias2[q * 4 + 0];
  float o1 = a1 * inv + bias2[q * 4 + 1];
  float o2 = a2 * inv + bias2[q * 4 + 2];
  float o3 = a3 * inv + bias2[q * 4 + 3];

  float m4 = fmaxf(fmaxf(o0, o1), fmaxf(o2, o3));
  float mx = wave_max64(l < 10 ? m4 : -3.4e38f);
  float se = wave_sum64(l < 10 ? __expf(o0 - mx) + __expf(o1 - mx) +
                                 __expf(o2 - mx) + __expf(o3 - mx) : 0.f);
  float ls = logf(se);
  if (l < 10)
    *(float4*)&outp[(size_t)n * 40 + q * 4] =
        make_float4(o0 - mx - ls, o1 - mx - ls, o2 - mx - ls, o3 - mx - ls);
}

// ---------------------------------------------------------------------------
extern "C" void kernel_launch(void* const* d_in, const int* in_sizes, int n_in,
                              void* d_out, int out_size, void* d_ws, size_t ws_size,
                              hipStream_t stream)
{
  const float* x        = (const float*)d_in[0];
  const int*   ei       = (const int*)d_in[1];
  const float* W1       = (const float*)d_in[2];
  const float* att_src1 = (const float*)d_in[3];
  const float* att_dst1 = (const float*)d_in[4];
  const float* bias1    = (const float*)d_in[5];
  const float* bn_gamma = (const float*)d_in[6];
  const float* bn_beta  = (const float*)d_in[7];
  const float* bn_mean  = (const float*)d_in[8];
  const float* bn_var   = (const float*)d_in[9];
  const float* W2       = (const float*)d_in[10];
  const float* att_src2 = (const float*)d_in[11];
  const float* att_dst2 = (const float*)d_in[12];
  const float* bias2    = (const float*)d_in[13];
  const float* W_skip   = (const float*)d_in[14];
  const float* b_skip   = (const float*)d_in[15];

  const int N = in_sizes[0] / 128;
  const int E = in_sizes[1] / 2;
  const int T = E + N;
  const int NB = (N + BMASK) >> BSH;   // 196

  char* p = (char*)d_ws;
  auto alloc = [&](size_t bytes) { char* q = p; p += (bytes + 255) & ~255ull; return q; };
  unsigned short* h1f8 = (unsigned short*)alloc((size_t)N * 128);   // fp8 [N][128]
  unsigned* hpostb = (unsigned*)alloc((size_t)N * 64 * 4);          // bf16 [N][128]
  unsigned* identb = (unsigned*)alloc((size_t)N * 64 * 4);          // bf16 [N][128]
  float* as1     = (float*)alloc((size_t)N * 8 * 4);
  float* ad1     = (float*)alloc((size_t)N * 8 * 4);
  float* Mext    = (float*)alloc(128 * 16 * 4);
  float* M2ext   = (float*)alloc(128 * 2 * 4);
  int*   starts  = (int*)alloc((size_t)N * 4);
  int*   ends    = (int*)alloc((size_t)N * 4);
  unsigned* pkbuf= (unsigned*)alloc((size_t)NB * BCAP * 4);
  int*   ssrc    = (int*)alloc((size_t)NB * BCAP * 4);
  int*   bcur    = (int*)alloc((size_t)NB * 4);
  // layer-2 reuse of dead layer-1 buffers (h1f8/as1/ad1 dead after agg1)
  unsigned* h2a8  = (unsigned*)h1f8;                          // [N][8] uints = N*32 B
  unsigned* h2b28 = (unsigned*)((char*)h1f8 + (size_t)N * 32); // [N][2] uints = N*8 B
  float* as2 = as1;
  float* ad2 = ad1;

  const int* ei_src = ei;
  const int* ei_dst = ei + E;

  prep_kernel<<<1, 256, 0, stream>>>(W1, att_src1, att_dst1, Mext,
                                     W2, att_src2, att_dst2, M2ext,
                                     bcur, NB);

  const int G1 = (N + 127) / 128;
  int NBLK_A = (T + CH_MAX - 1) / CH_MAX;
  if (NBLK_A < 512) NBLK_A = 512;
  const int chunk = (T + NBLK_A - 1) / NBLK_A;
  gemm1_scatter_kernel<<<G1 + NBLK_A, 256, 0, stream>>>(
      x, W1, W_skip, b_skip, Mext, h1f8, identb, as1, ad1, N,
      ei_src, ei_dst, bcur, pkbuf, E, T, chunk, NB, G1);

  passB_kernel<<<NB, 256, 0, stream>>>(pkbuf, bcur, starts, ends, ssrc, N);

  agg1_kernel<<<(N + 3) / 4, 256, 0, stream>>>(starts, ends, ssrc, as1, ad1, h1f8,
                                               bias1, bn_gamma, bn_beta, bn_mean, bn_var,
                                               identb, hpostb, N);
  gemm2_kernel<<<(N + 127) / 128, 256, 0, stream>>>(hpostb, W2, M2ext,
                                                    h2a8, h2b28, as2, ad2, N);
  agg2_kernel<<<(N + 3) / 4, 256, 0, stream>>>(starts, ends, ssrc, as2, ad2,
                                               h2a8, h2b28, bias2,
                                               (float*)d_out, N);
}

// Round 15
// 230.285 us; speedup vs baseline: 1.1279x; 1.0068x over previous
//
#include <hip/hip_runtime.h>
#include <math.h>

#define NEG_SLOPE 0.2f
#define BN_EPS 1e-5f
#define BSH 9
#define BMASK 511
#define LOG2E 1.44269504088896f
#define BCAP 12288
#define CH_MAX 3400

typedef __attribute__((ext_vector_type(8))) short short8;
typedef __attribute__((ext_vector_type(4))) float f32x4;
typedef __attribute__((ext_vector_type(2))) float f32x2;

__device__ __forceinline__ float wave_max64(float v) {
  #pragma unroll
  for (int o = 32; o; o >>= 1) v = fmaxf(v, __shfl_xor(v, o, 64));
  return v;
}
__device__ __forceinline__ float wave_sum64(float v) {
  #pragma unroll
  for (int o = 32; o; o >>= 1) v += __shfl_xor(v, o, 64);
  return v;
}

__device__ __forceinline__ unsigned pack2bf(float a, float b) {
  unsigned ua = __float_as_uint(a);
  unsigned ub = __float_as_uint(b);
  ua = ua + 0x7fffu + ((ua >> 16) & 1u);
  ub = ub + 0x7fffu + ((ub >> 16) & 1u);
  return (ua >> 16) | (ub & 0xffff0000u);
}
__device__ __forceinline__ float bf_lo(unsigned u) { return __uint_as_float(u << 16); }
__device__ __forceinline__ float bf_hi(unsigned u) { return __uint_as_float(u & 0xffff0000u); }

union U8 { short8 s; uint4 u; };

// ---------------------------------------------------------------------------
// prep: Mext/M2ext (prescaled by log2e) + zero bcur.
// ---------------------------------------------------------------------------
__global__ void prep_kernel(const float* __restrict__ W1,
                            const float* __restrict__ att_s,
                            const float* __restrict__ att_d,
                            float* __restrict__ Mext,
                            const float* __restrict__ W2,
                            const float* __restrict__ att_s2,
                            const float* __restrict__ att_d2,
                            float* __restrict__ M2ext,
                            int* __restrict__ bcur, int NB)
{
  int k = threadIdx.x;   // 0..255
  if (k < NB) bcur[k] = 0;
  if (k >= 128) return;
  #pragma unroll
  for (int h = 0; h < 8; ++h) {
    float s = 0.f, d = 0.f;
    #pragma unroll
    for (int c = 0; c < 16; ++c) {
      float w = W1[k * 128 + h * 16 + c];
      s += w * att_s[h * 16 + c];
      d += w * att_d[h * 16 + c];
    }
    Mext[k * 16 + h] = s * LOG2E;
    Mext[k * 16 + 8 + h] = d * LOG2E;
  }
  float s2 = 0.f, d2 = 0.f;
  #pragma unroll
  for (int c = 0; c < 40; ++c) {
    float w = W2[k * 40 + c];
    s2 += w * att_s2[c];
    d2 += w * att_d2[c];
  }
  M2ext[k * 2] = s2 * LOG2E;
  M2ext[k * 2 + 1] = d2 * LOG2E;
}

// ---------------------------------------------------------------------------
// FUSED gemm1 + scatterA (single-pass scatter via LDS staging).
// ---------------------------------------------------------------------------
__global__ __launch_bounds__(256) void gemm1_scatter_kernel(
    const float* __restrict__ X, const float* __restrict__ W1,
    const float* __restrict__ Wsk, const float* __restrict__ bsk,
    const float* __restrict__ Mext,
    unsigned short* __restrict__ h1f8, unsigned* __restrict__ identb,
    float* __restrict__ alpha_s, float* __restrict__ alpha_d, int N,
    const int* __restrict__ esrc, const int* __restrict__ edst,
    int* __restrict__ bcur, unsigned* __restrict__ pkbuf,
    int E, int T, int chunk, int NB, int G1)
{
  __shared__ uint4 Asm4[2048];           // 32 KB (gemm1 tile / scatter scratch)
  const int t = threadIdx.x;

  if ((int)blockIdx.x >= G1) {
    int* hist  = (int*)Asm4;
    int* lbase = hist + 256;
    int* lcur  = hist + 512;
    unsigned* spk = (unsigned*)(hist + 768);
    unsigned char* sbk = (unsigned char*)(spk + CH_MAX);
    const int bid = (int)blockIdx.x - G1;
    hist[t] = 0;
    __syncthreads();
    int s0 = bid * chunk;
    int s1 = min(s0 + chunk, T);
    for (int i = s0 + t; i < s1; i += 256) {
      int d, s;
      if (i < E) { d = edst[i]; s = esrc[i]; } else { d = s = i - E; }
      int b = d >> BSH;
      int li = i - s0;
      spk[li] = ((unsigned)(d & BMASK) << 17) | (unsigned)s;
      sbk[li] = (unsigned char)b;
      atomicAdd(&hist[b], 1);
    }
    __syncthreads();
    if (t < NB) {
      int h = hist[t];
      lbase[t] = t * BCAP + (h ? atomicAdd(&bcur[t], h) : 0);
      lcur[t] = 0;
    }
    __syncthreads();
    const int cnt2 = s1 - s0;
    for (int li = t; li < cnt2; li += 256) {
      int b = sbk[li];
      int p = lbase[b] + atomicAdd(&lcur[b], 1);
      pkbuf[p] = spk[li];
    }
    return;
  }

  // -------------------- gemm1 path --------------------
  const int l = t & 63, wave = t >> 6;
  const int lx = l & 15, ly = l >> 4;
  const int row0 = blockIdx.x * 128;
  const int wn0 = wave * 64;

  short8 b[4][4];
  short8 b4[4] = {};
  #pragma unroll
  for (int nf = 0; nf < 4; ++nf) {
    int c = wn0 + nf * 16 + lx;
    const float* bp = (c < 128) ? (W1 + c) : (Wsk + c - 128);
    #pragma unroll
    for (int kf = 0; kf < 4; ++kf) {
      int k0 = kf * 32 + ly * 8;
      U8 f;
      f.u.x = pack2bf(bp[(k0 + 0) * 128], bp[(k0 + 1) * 128]);
      f.u.y = pack2bf(bp[(k0 + 2) * 128], bp[(k0 + 3) * 128]);
      f.u.z = pack2bf(bp[(k0 + 4) * 128], bp[(k0 + 5) * 128]);
      f.u.w = pack2bf(bp[(k0 + 6) * 128], bp[(k0 + 7) * 128]);
      b[nf][kf] = f.s;
    }
  }
  if (wave == 0) {
    const float* bp = Mext + lx;
    #pragma unroll
    for (int kf = 0; kf < 4; ++kf) {
      int k0 = kf * 32 + ly * 8;
      U8 f;
      f.u.x = pack2bf(bp[(k0 + 0) * 16], bp[(k0 + 1) * 16]);
      f.u.y = pack2bf(bp[(k0 + 2) * 16], bp[(k0 + 3) * 16]);
      f.u.z = pack2bf(bp[(k0 + 4) * 16], bp[(k0 + 5) * 16]);
      f.u.w = pack2bf(bp[(k0 + 6) * 16], bp[(k0 + 7) * 16]);
      b4[kf] = f.s;
    }
  }

  {
    int rl = t >> 1;
    int half = t & 1;
    int r = row0 + rl;
    const float* xp = X + (size_t)r * 128 + half * 64;
    #pragma unroll
    for (int i = 0; i < 8; ++i) {
      float4 f0 = make_float4(0.f, 0.f, 0.f, 0.f), f1 = f0;
      if (r < N) {
        f0 = *(const float4*)(xp + i * 8);
        f1 = *(const float4*)(xp + i * 8 + 4);
      }
      uint4 u;
      u.x = pack2bf(f0.x, f0.y); u.y = pack2bf(f0.z, f0.w);
      u.z = pack2bf(f1.x, f1.y); u.w = pack2bf(f1.z, f1.w);
      int woff = (rl * 256 + half * 128 + i * 16) ^ ((rl & 7) << 4);
      *(uint4*)((char*)Asm4 + woff) = u;
    }
  }
  __syncthreads();

  float bval[4];
  if (wave >= 2) {
    #pragma unroll
    for (int nf = 0; nf < 4; ++nf) bval[nf] = bsk[(wave - 2) * 64 + nf * 16 + lx];
  }

  for (int mf = 0; mf < 8; ++mf) {
    short8 a[4];
    int rowl = mf * 16 + lx;
    #pragma unroll
    for (int kf = 0; kf < 4; ++kf)
      a[kf] = *(short8*)((char*)Asm4 + ((rowl * 256 + kf * 64 + ly * 16) ^ ((lx & 7) << 4)));

    int rbase = row0 + mf * 16 + ly * 4;

    #pragma unroll
    for (int nf = 0; nf < 4; ++nf) {
      f32x4 acc = {0.f, 0.f, 0.f, 0.f};
      #pragma unroll
      for (int kf = 0; kf < 4; ++kf)
        acc = __builtin_amdgcn_mfma_f32_16x16x32_bf16(a[kf], b[nf][kf], acc, 0, 0, 0);
      if (wave < 2) {
        int c = wn0 + nf * 16 + lx;
        #pragma unroll
        for (int reg = 0; reg < 4; ++reg) {
          float v = acc[reg];
          float vp = __shfl_xor(v, 1, 64);
          int r = rbase + reg;
          if (!(lx & 1) && r < N) {
            int u = __builtin_amdgcn_cvt_pk_fp8_f32(v, vp, 0, false);
            *(unsigned short*)((char*)h1f8 + (unsigned)r * 128u + (unsigned)c) =
                (unsigned short)u;
          }
        }
      } else {
        int c = (wave - 2) * 64 + nf * 16 + lx;
        #pragma unroll
        for (int reg = 0; reg < 4; ++reg) {
          float v = acc[reg] + bval[nf];
          float vp = __shfl_xor(v, 1, 64);
          int r = rbase + reg;
          if (!(lx & 1) && r < N)
            identb[(unsigned)r * 64u + (unsigned)(c >> 1)] = pack2bf(v, vp);
        }
      }
    }

    if (wave == 0) {
      f32x4 acc = {0.f, 0.f, 0.f, 0.f};
      #pragma unroll
      for (int kf = 0; kf < 4; ++kf)
        acc = __builtin_amdgcn_mfma_f32_16x16x32_bf16(a[kf], b4[kf], acc, 0, 0, 0);
      #pragma unroll
      for (int reg = 0; reg < 4; ++reg) {
        int r = rbase + reg;
        if (r < N) {
          if (lx < 8) alpha_s[(size_t)r * 8 + lx] = acc[reg];
          else        alpha_d[(size_t)r * 8 + (lx - 8)] = acc[reg];
        }
      }
    }
  }
}

// ---------------------------------------------------------------------------
// passB: one block per bucket.
// ---------------------------------------------------------------------------
__global__ __launch_bounds__(256) void passB_kernel(
    const unsigned* __restrict__ pkbuf, const int* __restrict__ bcnt,
    int* __restrict__ starts, int* __restrict__ ends,
    int* __restrict__ ssrc, int N)
{
  __shared__ int cnt[512];
  __shared__ int ps[256];
  __shared__ int cur[512];
  const int t = threadIdx.x;
  const int b = blockIdx.x;
  const int bs = b * BCAP;
  const int be = bs + bcnt[b];

  cnt[t] = 0; cnt[t + 256] = 0;
  __syncthreads();
  for (int i = bs + t; i < be; i += 256)
    atomicAdd(&cnt[pkbuf[i] >> 17], 1);
  __syncthreads();

  int a = cnt[2 * t], b2 = cnt[2 * t + 1];
  ps[t] = a + b2;
  __syncthreads();
  for (int d = 1; d < 256; d <<= 1) {
    int u = (t >= d) ? ps[t - d] : 0;
    __syncthreads();
    ps[t] += u;
    __syncthreads();
  }
  int excl = ps[t] - (a + b2);
  cur[2 * t] = excl;
  cur[2 * t + 1] = excl + a;
  __syncthreads();

  const int node0 = b << BSH;
  {
    int n0 = node0 + 2 * t, n1 = node0 + 2 * t + 1;
    if (n0 < N) { starts[n0] = bs + cur[2 * t];     ends[n0] = bs + cur[2 * t] + a; }
    if (n1 < N) { starts[n1] = bs + cur[2 * t + 1]; ends[n1] = bs + cur[2 * t + 1] + b2; }
  }
  __syncthreads();

  for (int i = bs + t; i < be; i += 256) {
    unsigned pk = pkbuf[i];
    int d = pk >> 17;
    int p = atomicAdd(&cur[d], 1);
    ssrc[bs + p] = (int)(pk & 0x1FFFFu);
  }
}

// ---------------------------------------------------------------------------
// Layer-1 aggregation, two-phase (TRANSPOSED phase-1: edge slot = l&7,
// head = l>>3). ew broadcast via static ds_swizzle (no VGPR addr); the
// denominator reduce (shfl_xor 1,2,4) lands in-place -> no final bpermute.
// Packed fp8 decode (cvt_pk_f32_fp8) + float2 accumulators.
// ---------------------------------------------------------------------------
__global__ __launch_bounds__(256) void agg1_kernel(
    const int* __restrict__ starts, const int* __restrict__ ends,
    const int* __restrict__ ssrc,
    const float* __restrict__ as1, const float* __restrict__ ad1,
    const unsigned short* __restrict__ h1f8,
    const float* __restrict__ bias1, const float* __restrict__ gamma,
    const float* __restrict__ beta, const float* __restrict__ mean,
    const float* __restrict__ var,
    const unsigned* __restrict__ identb, unsigned* __restrict__ hpostb, int N)
{
  const int w = threadIdx.x >> 6, l = threadIdx.x & 63;
  const int n = blockIdx.x * 4 + w;
  if (n >= N) return;
  const int e8 = l & 7;            // phase-1 edge slot (TRANSPOSED)
  const int hh = l >> 3;           // phase-1 head == phase-2 head
  const int hb4 = (l & 56) << 2;   // tail bpermute base: ((l>>3)*8)*4
  const int c0 = l * 2;
  const unsigned l2 = (unsigned)(l * 2);
  const float adp = ad1[(unsigned)n * 8u + (unsigned)hh];
  const int jb = starts[n], je = ends[n];

  const float bb0 = bias1[c0], bb1 = bias1[c0 + 1];
  const float sc0 = gamma[c0] * rsqrtf(var[c0] + BN_EPS);
  const float sc1 = gamma[c0 + 1] * rsqrtf(var[c0 + 1] + BN_EPS);
  const float mn0 = mean[c0], mn1 = mean[c0 + 1];
  const float bt0 = beta[c0], bt1 = beta[c0 + 1];

  const char* h1c = (const char*)h1f8;

  float dsum = 0.f;
  f32x2 acc2 = {0.f, 0.f};

  // ew for edge K, head l>>3 lives in lane (l&56)|K -> ds_swizzle BitMode
  // offset = and(0x18) | (or=K)<<5  (lane[5] preserved automatically)
#define PHASE2(K, SVEC, EW) { \
    unsigned sk = (unsigned)__builtin_amdgcn_readlane(SVEC, (K)); \
    float ewk = __uint_as_float((unsigned) \
        __builtin_amdgcn_ds_swizzle((int)__float_as_uint(EW), 0x18 | ((K) << 5))); \
    unsigned u8 = *(const unsigned short*)(h1c + ((size_t)sk << 7) + l2); \
    f32x2 hv = __builtin_amdgcn_cvt_pk_f32_fp8((int)u8, false); \
    acc2 += ewk * hv; }

  int j = jb;
  for (; j + 8 <= je; j += 8) {
    int svec = ssrc[j + e8];
    float e = as1[(unsigned)svec * 8u + (unsigned)hh] + adp;
    e = fmaxf(e, NEG_SLOPE * e);
    float ew = exp2f(e);
    dsum += ew;
    PHASE2(0, svec, ew) PHASE2(1, svec, ew) PHASE2(2, svec, ew) PHASE2(3, svec, ew)
    PHASE2(4, svec, ew) PHASE2(5, svec, ew) PHASE2(6, svec, ew) PHASE2(7, svec, ew)
  }
  int rem = je - j;
  if (rem > 0) {
    int jj = j + (e8 < rem ? e8 : 0);
    int svec = ssrc[jj];
    float e = as1[(unsigned)svec * 8u + (unsigned)hh] + adp;
    e = fmaxf(e, NEG_SLOPE * e);
    float ew = (e8 < rem) ? exp2f(e) : 0.f;
    dsum += ew;
    for (int k = 0; k < rem; ++k) {
      unsigned sk = (unsigned)__builtin_amdgcn_readlane(svec, k);
      float ewk = __uint_as_float(
          __builtin_amdgcn_ds_bpermute(hb4 + (k << 2), __float_as_uint(ew)));
      unsigned u8 = *(const unsigned short*)(h1c + ((size_t)sk << 7) + l2);
      f32x2 hv = __builtin_amdgcn_cvt_pk_f32_fp8((int)u8, false);
      acc2 += ewk * hv;
    }
  }
#undef PHASE2

  // denominator: reduce over the 8 edge slots (bits 0..2) -> each lane ends
  // with denom for its own head (l>>3). No transpose needed.
  dsum += __shfl_xor(dsum, 1, 64);
  dsum += __shfl_xor(dsum, 2, 64);
  dsum += __shfl_xor(dsum, 4, 64);

  float inv = 1.f / (dsum + 1e-16f);
  unsigned uid = identb[(unsigned)n * 64u + (unsigned)l];
  float o0 = acc2.x * inv + bb0;
  float o1 = acc2.y * inv + bb1;
  o0 = (o0 - mn0) * sc0 + bt0;
  o1 = (o1 - mn1) * sc1 + bt1;
  o0 = o0 > 0.f ? o0 : expm1f(o0);
  o1 = o1 > 0.f ? o1 : expm1f(o1);
  o0 += bf_lo(uid); o1 += bf_hi(uid);
  hpostb[(unsigned)n * 64u + (unsigned)l] = pack2bf(o0, o1);
}

// ---------------------------------------------------------------------------
// MFMA GEMM2, LDS-free. FP8 h2 split: h2a8 [N][8 uints] + h2b28 [N][2 uints].
// ---------------------------------------------------------------------------
__global__ __launch_bounds__(256) void gemm2_kernel(
    const unsigned* __restrict__ hpostb, const float* __restrict__ W2,
    const float* __restrict__ M2ext,
    unsigned* __restrict__ h2a8, unsigned* __restrict__ h2b28,
    float* __restrict__ as2, float* __restrict__ ad2, int N)
{
  const int t = threadIdx.x;
  const int l = t & 63, wave = t >> 6;
  const int lx = l & 15, ly = l >> 4;
  const int row0 = blockIdx.x * 128;

  short8 b[3][4];
  short8 b4[4];
  {
    #pragma unroll
    for (int nf = 0; nf < 3; ++nf) {
      int col = nf * 16 + lx;
      bool v = col < 40;
      const float* bp = W2 + (v ? col : 0);
      #pragma unroll
      for (int kf = 0; kf < 4; ++kf) {
        int k0 = kf * 32 + ly * 8;
        U8 f;
        if (v) {
          f.u.x = pack2bf(bp[(k0 + 0) * 40], bp[(k0 + 1) * 40]);
          f.u.y = pack2bf(bp[(k0 + 2) * 40], bp[(k0 + 3) * 40]);
          f.u.z = pack2bf(bp[(k0 + 4) * 40], bp[(k0 + 5) * 40]);
          f.u.w = pack2bf(bp[(k0 + 6) * 40], bp[(k0 + 7) * 40]);
        } else {
          f.u = make_uint4(0, 0, 0, 0);
        }
        b[nf][kf] = f.s;
      }
    }
    bool va = lx < 2;
    const float* bp = M2ext + (va ? lx : 0);
    #pragma unroll
    for (int kf = 0; kf < 4; ++kf) {
      int k0 = kf * 32 + ly * 8;
      U8 f;
      if (va) {
        f.u.x = pack2bf(bp[(k0 + 0) * 2], bp[(k0 + 1) * 2]);
        f.u.y = pack2bf(bp[(k0 + 2) * 2], bp[(k0 + 3) * 2]);
        f.u.z = pack2bf(bp[(k0 + 4) * 2], bp[(k0 + 5) * 2]);
        f.u.w = pack2bf(bp[(k0 + 6) * 2], bp[(k0 + 7) * 2]);
      } else {
        f.u = make_uint4(0, 0, 0, 0);
      }
      b4[kf] = f.s;
    }
  }

  #pragma unroll
  for (int i2 = 0; i2 < 2; ++i2) {
    int mf = wave * 2 + i2;
    int arow = row0 + mf * 16 + lx;
    short8 a[4];
    #pragma unroll
    for (int kf = 0; kf < 4; ++kf) {
      U8 f;
      f.u = make_uint4(0, 0, 0, 0);
      if (arow < N)
        f.u = *(const uint4*)(hpostb + (unsigned)arow * 64u + (unsigned)(kf * 16 + ly * 4));
      a[kf] = f.s;
    }

    int rbase = row0 + mf * 16 + ly * 4;

    #pragma unroll
    for (int nf = 0; nf < 3; ++nf) {
      f32x4 acc = {0.f, 0.f, 0.f, 0.f};
      #pragma unroll
      for (int kf = 0; kf < 4; ++kf)
        acc = __builtin_amdgcn_mfma_f32_16x16x32_bf16(a[kf], b[nf][kf], acc, 0, 0, 0);
      int c = nf * 16 + lx;
      #pragma unroll
      for (int reg = 0; reg < 4; ++reg) {
        float v = acc[reg];
        float v1 = __shfl_xor(v, 1, 64);
        float v2 = __shfl_xor(v, 2, 64);
        float v3 = __shfl_xor(v1, 2, 64);
        int r = rbase + reg;
        if (r < N && c < 40 && !(lx & 3)) {
          int u = __builtin_amdgcn_cvt_pk_fp8_f32(v, v1, 0, false);
          u = __builtin_amdgcn_cvt_pk_fp8_f32(v2, v3, u, true);
          int c4 = c >> 2;
          if (c < 32) h2a8[((unsigned)r << 3) + (unsigned)c4] = (unsigned)u;
          else        h2b28[((unsigned)r << 1) + (unsigned)(c4 - 8)] = (unsigned)u;
        }
      }
    }
    {
      f32x4 acc = {0.f, 0.f, 0.f, 0.f};
      #pragma unroll
      for (int kf = 0; kf < 4; ++kf)
        acc = __builtin_amdgcn_mfma_f32_16x16x32_bf16(a[kf], b4[kf], acc, 0, 0, 0);
      #pragma unroll
      for (int reg = 0; reg < 4; ++reg) {
        int r = rbase + reg;
        if (r < N) {
          if (lx == 0) as2[r] = acc[reg];
          else if (lx == 1) ad2[r] = acc[reg];
        }
      }
    }
  }
}

// ---------------------------------------------------------------------------
// Layer-2 aggregation + bias2 + fused log_softmax. FP8 h2 gather,
// 6 edge-groups of 10 lanes, x2 unrolled; packed fp8 decode.
// ---------------------------------------------------------------------------
__global__ __launch_bounds__(256) void agg2_kernel(
    const int* __restrict__ starts, const int* __restrict__ ends,
    const int* __restrict__ ssrc,
    const float* __restrict__ as2, const float* __restrict__ ad2,
    const unsigned* __restrict__ h2a8, const unsigned* __restrict__ h2b28,
    const float* __restrict__ bias2,
    float* __restrict__ outp, int N)
{
  const int w = threadIdx.x >> 6, l = threadIdx.x & 63;
  const int n = blockIdx.x * 4 + w;
  if (n >= N) return;
  const int g = l / 10;            // 0..5 (6 for idle lanes 60-63)
  const int q = l - g * 10;        // dword index 0..9
  const bool act = l < 60;
  const float ad = ad2[n];         // prescaled
  const int jb = starts[n], je = ends[n];

  const char* hbase = (q < 8) ? ((const char*)h2a8 + (unsigned)q * 4u)
                              : ((const char*)h2b28 + (unsigned)(q - 8) * 4u);
  const unsigned hshift = (q < 8) ? 5u : 3u;
  const char* as2c = (const char*)as2;

  float dsum = 0.f;
  f32x2 acc01 = {0.f, 0.f}, acc23 = {0.f, 0.f};

#define EDGE2(JJ, GUARD) { \
    bool v_ = act && (GUARD); \
    unsigned s = v_ ? (unsigned)ssrc[JJ] : 0u; \
    float e = *(const float*)(as2c + (s << 2)) + ad; \
    e = fmaxf(e, NEG_SLOPE * e); \
    float ex = v_ ? exp2f(e) : 0.f; \
    unsigned u = *(const unsigned*)(hbase + ((size_t)s << hshift)); \
    dsum += ex; \
    f32x2 lo = __builtin_amdgcn_cvt_pk_f32_fp8((int)u, false); \
    f32x2 hi = __builtin_amdgcn_cvt_pk_f32_fp8((int)u, true); \
    acc01 += ex * lo; \
    acc23 += ex * hi; }

  int j = jb;
  for (; j + 12 <= je; j += 12) {
    EDGE2(j + g, true)
    EDGE2(j + 6 + g, true)
  }
  for (; j < je; j += 6) {
    EDGE2(j + g, (j + g) < je)
  }
#undef EDGE2

  float a0 = acc01.x, a1 = acc01.y, a2 = acc23.x, a3 = acc23.y;

  // combine the 6 groups (stride 10) into lanes 0..9
#define COMB(A) { \
    float t_ = A + __shfl(A, l + 30, 64); \
    A = t_ + __shfl(t_, l + 10, 64) + __shfl(t_, l + 20, 64); }
  COMB(a0) COMB(a1) COMB(a2) COMB(a3) COMB(dsum)
#undef COMB

  float inv = 1.f / (dsum + 1e-16f);
  float o0 = a0 * inv + bias2[q * 4 + 0];
  float o1 = a1 * inv + bias2[q * 4 + 1];
  float o2 = a2 * inv + bias2[q * 4 + 2];
  float o3 = a3 * inv + bias2[q * 4 + 3];

  float m4 = fmaxf(fmaxf(o0, o1), fmaxf(o2, o3));
  float mx = wave_max64(l < 10 ? m4 : -3.4e38f);
  float se = wave_sum64(l < 10 ? __expf(o0 - mx) + __expf(o1 - mx) +
                                 __expf(o2 - mx) + __expf(o3 - mx) : 0.f);
  float ls = logf(se);
  if (l < 10)
    *(float4*)&outp[(size_t)n * 40 + q * 4] =
        make_float4(o0 - mx - ls, o1 - mx - ls, o2 - mx - ls, o3 - mx - ls);
}

// ---------------------------------------------------------------------------
extern "C" void kernel_launch(void* const* d_in, const int* in_sizes, int n_in,
                              void* d_out, int out_size, void* d_ws, size_t ws_size,
                              hipStream_t stream)
{
  const float* x        = (const float*)d_in[0];
  const int*   ei       = (const int*)d_in[1];
  const float* W1       = (const float*)d_in[2];
  const float* att_src1 = (const float*)d_in[3];
  const float* att_dst1 = (const float*)d_in[4];
  const float* bias1    = (const float*)d_in[5];
  const float* bn_gamma = (const float*)d_in[6];
  const float* bn_beta  = (const float*)d_in[7];
  const float* bn_mean  = (const float*)d_in[8];
  const float* bn_var   = (const float*)d_in[9];
  const float* W2       = (const float*)d_in[10];
  const float* att_src2 = (const float*)d_in[11];
  const float* att_dst2 = (const float*)d_in[12];
  const float* bias2    = (const float*)d_in[13];
  const float* W_skip   = (const float*)d_in[14];
  const float* b_skip   = (const float*)d_in[15];

  const int N = in_sizes[0] / 128;
  const int E = in_sizes[1] / 2;
  const int T = E + N;
  const int NB = (N + BMASK) >> BSH;   // 196

  char* p = (char*)d_ws;
  auto alloc = [&](size_t bytes) { char* q = p; p += (bytes + 255) & ~255ull; return q; };
  unsigned short* h1f8 = (unsigned short*)alloc((size_t)N * 128);   // fp8 [N][128]
  unsigned* hpostb = (unsigned*)alloc((size_t)N * 64 * 4);          // bf16 [N][128]
  unsigned* identb = (unsigned*)alloc((size_t)N * 64 * 4);          // bf16 [N][128]
  float* as1     = (float*)alloc((size_t)N * 8 * 4);
  float* ad1     = (float*)alloc((size_t)N * 8 * 4);
  float* Mext    = (float*)alloc(128 * 16 * 4);
  float* M2ext   = (float*)alloc(128 * 2 * 4);
  int*   starts  = (int*)alloc((size_t)N * 4);
  int*   ends    = (int*)alloc((size_t)N * 4);
  unsigned* pkbuf= (unsigned*)alloc((size_t)NB * BCAP * 4);
  int*   ssrc    = (int*)alloc((size_t)NB * BCAP * 4);
  int*   bcur    = (int*)alloc((size_t)NB * 4);
  // layer-2 reuse of dead layer-1 buffers (h1f8/as1/ad1 dead after agg1)
  unsigned* h2a8  = (unsigned*)h1f8;                          // [N][8] uints
  unsigned* h2b28 = (unsigned*)((char*)h1f8 + (size_t)N * 32); // [N][2] uints
  float* as2 = as1;
  float* ad2 = ad1;

  const int* ei_src = ei;
  const int* ei_dst = ei + E;

  prep_kernel<<<1, 256, 0, stream>>>(W1, att_src1, att_dst1, Mext,
                                     W2, att_src2, att_dst2, M2ext,
                                     bcur, NB);

  const int G1 = (N + 127) / 128;
  int NBLK_A = (T + CH_MAX - 1) / CH_MAX;
  if (NBLK_A < 512) NBLK_A = 512;
  const int chunk = (T + NBLK_A - 1) / NBLK_A;
  gemm1_scatter_kernel<<<G1 + NBLK_A, 256, 0, stream>>>(
      x, W1, W_skip, b_skip, Mext, h1f8, identb, as1, ad1, N,
      ei_src, ei_dst, bcur, pkbuf, E, T, chunk, NB, G1);

  passB_kernel<<<NB, 256, 0, stream>>>(pkbuf, bcur, starts, ends, ssrc, N);

  agg1_kernel<<<(N + 3) / 4, 256, 0, stream>>>(starts, ends, ssrc, as1, ad1, h1f8,
                                               bias1, bn_gamma, bn_beta, bn_mean, bn_var,
                                               identb, hpostb, N);
  gemm2_kernel<<<(N + 127) / 128, 256, 0, stream>>>(hpostb, W2, M2ext,
                                                    h2a8, h2b28, as2, ad2, N);
  agg2_kernel<<<(N + 3) / 4, 256, 0, stream>>>(starts, ends, ssrc, as2, ad2,
                                               h2a8, h2b28, bias2,
                                               (float*)d_out, N);
}

// Round 16
// 222.407 us; speedup vs baseline: 1.1678x; 1.0354x over previous
//
#include <hip/hip_runtime.h>
#include <math.h>

#define NEG_SLOPE 0.2f
#define BN_EPS 1e-5f
#define BSH 9
#define BMASK 511
#define LOG2E 1.44269504088896f
#define BCAP 12288
#define CH_MAX 3400

typedef __attribute__((ext_vector_type(8))) short short8;
typedef __attribute__((ext_vector_type(4))) float f32x4;
typedef __attribute__((ext_vector_type(2))) float f32x2;

__device__ __forceinline__ float wave_max64(float v) {
  #pragma unroll
  for (int o = 32; o; o >>= 1) v = fmaxf(v, __shfl_xor(v, o, 64));
  return v;
}
__device__ __forceinline__ float wave_sum64(float v) {
  #pragma unroll
  for (int o = 32; o; o >>= 1) v += __shfl_xor(v, o, 64);
  return v;
}

__device__ __forceinline__ unsigned pack2bf(float a, float b) {
  unsigned ua = __float_as_uint(a);
  unsigned ub = __float_as_uint(b);
  ua = ua + 0x7fffu + ((ua >> 16) & 1u);
  ub = ub + 0x7fffu + ((ub >> 16) & 1u);
  return (ua >> 16) | (ub & 0xffff0000u);
}
__device__ __forceinline__ float bf_lo(unsigned u) { return __uint_as_float(u << 16); }
__device__ __forceinline__ float bf_hi(unsigned u) { return __uint_as_float(u & 0xffff0000u); }

union U8 { short8 s; uint4 u; };

// ---------------------------------------------------------------------------
// prep (4 blocks x 256): builds bf16 fragment-layout weight buffers so the
// GEMM kernels load B-frags with single uint4 loads instead of 8 strided
// scalar loads + packs per fragment.
//   Bbuf   [256][128] bf16 : col c<128 -> W1[k][c]; else Wsk[k][c-128]
//   Mextbuf[16][128]  bf16 : col h<8 -> (W1·att_s)[k][h]·log2e; h>=8 -> att_d
//   B2buf  [64][128]  bf16 : col<40 -> W2[k][col]; 48/49 -> M2ext s/d; else 0
// Block 0 also zeroes bcur.
// ---------------------------------------------------------------------------
__global__ __launch_bounds__(256) void prep_kernel(
    const float* __restrict__ W1, const float* __restrict__ Wsk,
    const float* __restrict__ att_s, const float* __restrict__ att_d,
    const float* __restrict__ W2,
    const float* __restrict__ att_s2, const float* __restrict__ att_d2,
    unsigned short* __restrict__ Bbuf, unsigned short* __restrict__ Mextbuf,
    unsigned short* __restrict__ B2buf,
    int* __restrict__ bcur, int NB)
{
  const int t = threadIdx.x;
  const int bid = blockIdx.x;

  if (bid == 0) {
    __shared__ float Ms[128][16];
    __shared__ float M2s[128][2];
    if (t < NB) bcur[t] = 0;
    if (t < 128) {
      int k = t;
      #pragma unroll
      for (int h = 0; h < 8; ++h) {
        float s = 0.f, d = 0.f;
        #pragma unroll
        for (int c = 0; c < 16; ++c) {
          float w = W1[k * 128 + h * 16 + c];
          s += w * att_s[h * 16 + c];
          d += w * att_d[h * 16 + c];
        }
        Ms[k][h] = s * LOG2E;
        Ms[k][8 + h] = d * LOG2E;
      }
      float s2 = 0.f, d2 = 0.f;
      #pragma unroll
      for (int c = 0; c < 40; ++c) {
        float w = W2[k * 40 + c];
        s2 += w * att_s2[c];
        d2 += w * att_d2[c];
      }
      M2s[k][0] = s2 * LOG2E;
      M2s[k][1] = d2 * LOG2E;
    }
    __syncthreads();
    unsigned* Mu = (unsigned*)Mextbuf;
    for (int idx = t; idx < 16 * 64; idx += 256) {
      int h = idx >> 6, u = idx & 63;
      Mu[h * 64 + u] = pack2bf(Ms[2 * u][h], Ms[2 * u + 1][h]);
    }
    unsigned* B2u = (unsigned*)B2buf;
    for (int idx = t; idx < 2 * 64; idx += 256) {
      int cc = idx >> 6, u = idx & 63;
      B2u[(48 + cc) * 64 + u] = pack2bf(M2s[2 * u][cc], M2s[2 * u + 1][cc]);
    }
  } else if (bid <= 2) {
    int c = (bid - 1) * 128 + (t >> 1);
    int half = t & 1;
    const float* src = (c < 128) ? (W1 + c) : (Wsk + (c - 128));
    unsigned* out = (unsigned*)Bbuf + c * 64 + half * 32;
    #pragma unroll 8
    for (int u = 0; u < 32; ++u) {
      int k = half * 64 + 2 * u;
      out[u] = pack2bf(src[(size_t)k * 128], src[(size_t)(k + 1) * 128]);
    }
  } else {
    unsigned* B2u = (unsigned*)B2buf;
    for (int idx = t; idx < 40 * 64; idx += 256) {
      int c = idx >> 6, u = idx & 63;
      B2u[c * 64 + u] = pack2bf(W2[(2 * u) * 40 + c], W2[(2 * u + 1) * 40 + c]);
    }
    for (int idx = t; idx < 22 * 64; idx += 256) {
      int zc = idx >> 6, u = idx & 63;
      int c = (zc < 8) ? (40 + zc) : (50 + (zc - 8));
      B2u[c * 64 + u] = 0;
    }
  }
}

// ---------------------------------------------------------------------------
// FUSED gemm1 + scatterA (single-pass scatter via LDS staging).
// gemm1: B-frags loaded straight from Bbuf/Mextbuf (uint4 each).
// ident now stored as fp8 e4m3.
// ---------------------------------------------------------------------------
__global__ __launch_bounds__(256) void gemm1_scatter_kernel(
    const float* __restrict__ X,
    const unsigned short* __restrict__ Bbuf,
    const unsigned short* __restrict__ Mextbuf,
    const float* __restrict__ bsk,
    unsigned short* __restrict__ h1f8, unsigned short* __restrict__ identf8,
    float* __restrict__ alpha_s, float* __restrict__ alpha_d, int N,
    const int* __restrict__ esrc, const int* __restrict__ edst,
    int* __restrict__ bcur, unsigned* __restrict__ pkbuf,
    int E, int T, int chunk, int NB, int G1)
{
  __shared__ uint4 Asm4[2048];           // 32 KB (gemm1 tile / scatter scratch)
  const int t = threadIdx.x;

  if ((int)blockIdx.x >= G1) {
    int* hist  = (int*)Asm4;
    int* lbase = hist + 256;
    int* lcur  = hist + 512;
    unsigned* spk = (unsigned*)(hist + 768);
    unsigned char* sbk = (unsigned char*)(spk + CH_MAX);
    const int bid = (int)blockIdx.x - G1;
    hist[t] = 0;
    __syncthreads();
    int s0 = bid * chunk;
    int s1 = min(s0 + chunk, T);
    for (int i = s0 + t; i < s1; i += 256) {
      int d, s;
      if (i < E) { d = edst[i]; s = esrc[i]; } else { d = s = i - E; }
      int b = d >> BSH;
      int li = i - s0;
      spk[li] = ((unsigned)(d & BMASK) << 17) | (unsigned)s;
      sbk[li] = (unsigned char)b;
      atomicAdd(&hist[b], 1);
    }
    __syncthreads();
    if (t < NB) {
      int h = hist[t];
      lbase[t] = t * BCAP + (h ? atomicAdd(&bcur[t], h) : 0);
      lcur[t] = 0;
    }
    __syncthreads();
    const int cnt2 = s1 - s0;
    for (int li = t; li < cnt2; li += 256) {
      int b = sbk[li];
      int p = lbase[b] + atomicAdd(&lcur[b], 1);
      pkbuf[p] = spk[li];
    }
    return;
  }

  // -------------------- gemm1 path --------------------
  const int l = t & 63, wave = t >> 6;
  const int lx = l & 15, ly = l >> 4;
  const int row0 = blockIdx.x * 128;
  const int wn0 = wave * 64;

  short8 b[4][4];
  short8 b4[4] = {};
  #pragma unroll
  for (int nf = 0; nf < 4; ++nf) {
    int c = wn0 + nf * 16 + lx;
    #pragma unroll
    for (int kf = 0; kf < 4; ++kf)
      b[nf][kf] = *(const short8*)(Bbuf + c * 128 + kf * 32 + ly * 8);
  }
  if (wave == 0) {
    #pragma unroll
    for (int kf = 0; kf < 4; ++kf)
      b4[kf] = *(const short8*)(Mextbuf + lx * 128 + kf * 32 + ly * 8);
  }

  {
    int rl = t >> 1;
    int half = t & 1;
    int r = row0 + rl;
    const float* xp = X + (size_t)r * 128 + half * 64;
    #pragma unroll
    for (int i = 0; i < 8; ++i) {
      float4 f0 = make_float4(0.f, 0.f, 0.f, 0.f), f1 = f0;
      if (r < N) {
        f0 = *(const float4*)(xp + i * 8);
        f1 = *(const float4*)(xp + i * 8 + 4);
      }
      uint4 u;
      u.x = pack2bf(f0.x, f0.y); u.y = pack2bf(f0.z, f0.w);
      u.z = pack2bf(f1.x, f1.y); u.w = pack2bf(f1.z, f1.w);
      int woff = (rl * 256 + half * 128 + i * 16) ^ ((rl & 7) << 4);
      *(uint4*)((char*)Asm4 + woff) = u;
    }
  }
  __syncthreads();

  float bval[4];
  if (wave >= 2) {
    #pragma unroll
    for (int nf = 0; nf < 4; ++nf) bval[nf] = bsk[(wave - 2) * 64 + nf * 16 + lx];
  }

  for (int mf = 0; mf < 8; ++mf) {
    short8 a[4];
    int rowl = mf * 16 + lx;
    #pragma unroll
    for (int kf = 0; kf < 4; ++kf)
      a[kf] = *(short8*)((char*)Asm4 + ((rowl * 256 + kf * 64 + ly * 16) ^ ((lx & 7) << 4)));

    int rbase = row0 + mf * 16 + ly * 4;

    #pragma unroll
    for (int nf = 0; nf < 4; ++nf) {
      f32x4 acc = {0.f, 0.f, 0.f, 0.f};
      #pragma unroll
      for (int kf = 0; kf < 4; ++kf)
        acc = __builtin_amdgcn_mfma_f32_16x16x32_bf16(a[kf], b[nf][kf], acc, 0, 0, 0);
      if (wave < 2) {
        int c = wn0 + nf * 16 + lx;
        #pragma unroll
        for (int reg = 0; reg < 4; ++reg) {
          float v = acc[reg];
          float vp = __shfl_xor(v, 1, 64);
          int r = rbase + reg;
          if (!(lx & 1) && r < N) {
            int u = __builtin_amdgcn_cvt_pk_fp8_f32(v, vp, 0, false);
            *(unsigned short*)((char*)h1f8 + (unsigned)r * 128u + (unsigned)c) =
                (unsigned short)u;
          }
        }
      } else {
        int c = (wave - 2) * 64 + nf * 16 + lx;
        #pragma unroll
        for (int reg = 0; reg < 4; ++reg) {
          float v = acc[reg] + bval[nf];
          float vp = __shfl_xor(v, 1, 64);
          int r = rbase + reg;
          if (!(lx & 1) && r < N) {
            int u = __builtin_amdgcn_cvt_pk_fp8_f32(v, vp, 0, false);
            *(unsigned short*)((char*)identf8 + (unsigned)r * 128u + (unsigned)c) =
                (unsigned short)u;
          }
        }
      }
    }

    if (wave == 0) {
      f32x4 acc = {0.f, 0.f, 0.f, 0.f};
      #pragma unroll
      for (int kf = 0; kf < 4; ++kf)
        acc = __builtin_amdgcn_mfma_f32_16x16x32_bf16(a[kf], b4[kf], acc, 0, 0, 0);
      #pragma unroll
      for (int reg = 0; reg < 4; ++reg) {
        int r = rbase + reg;
        if (r < N) {
          if (lx < 8) alpha_s[(size_t)r * 8 + lx] = acc[reg];
          else        alpha_d[(size_t)r * 8 + (lx - 8)] = acc[reg];
        }
      }
    }
  }
}

// ---------------------------------------------------------------------------
// passB: one block per bucket.
// ---------------------------------------------------------------------------
__global__ __launch_bounds__(256) void passB_kernel(
    const unsigned* __restrict__ pkbuf, const int* __restrict__ bcnt,
    int* __restrict__ starts, int* __restrict__ ends,
    int* __restrict__ ssrc, int N)
{
  __shared__ int cnt[512];
  __shared__ int ps[256];
  __shared__ int cur[512];
  const int t = threadIdx.x;
  const int b = blockIdx.x;
  const int bs = b * BCAP;
  const int be = bs + bcnt[b];

  cnt[t] = 0; cnt[t + 256] = 0;
  __syncthreads();
  for (int i = bs + t; i < be; i += 256)
    atomicAdd(&cnt[pkbuf[i] >> 17], 1);
  __syncthreads();

  int a = cnt[2 * t], b2 = cnt[2 * t + 1];
  ps[t] = a + b2;
  __syncthreads();
  for (int d = 1; d < 256; d <<= 1) {
    int u = (t >= d) ? ps[t - d] : 0;
    __syncthreads();
    ps[t] += u;
    __syncthreads();
  }
  int excl = ps[t] - (a + b2);
  cur[2 * t] = excl;
  cur[2 * t + 1] = excl + a;
  __syncthreads();

  const int node0 = b << BSH;
  {
    int n0 = node0 + 2 * t, n1 = node0 + 2 * t + 1;
    if (n0 < N) { starts[n0] = bs + cur[2 * t];     ends[n0] = bs + cur[2 * t] + a; }
    if (n1 < N) { starts[n1] = bs + cur[2 * t + 1]; ends[n1] = bs + cur[2 * t + 1] + b2; }
  }
  __syncthreads();

  for (int i = bs + t; i < be; i += 256) {
    unsigned pk = pkbuf[i];
    int d = pk >> 17;
    int p = atomicAdd(&cur[d], 1);
    ssrc[bs + p] = (int)(pk & 0x1FFFFu);
  }
}

// ---------------------------------------------------------------------------
// Layer-1 aggregation, two-phase (transposed phase-1), fp8 ident read.
// ---------------------------------------------------------------------------
__global__ __launch_bounds__(256) void agg1_kernel(
    const int* __restrict__ starts, const int* __restrict__ ends,
    const int* __restrict__ ssrc,
    const float* __restrict__ as1, const float* __restrict__ ad1,
    const unsigned short* __restrict__ h1f8,
    const float* __restrict__ bias1, const float* __restrict__ gamma,
    const float* __restrict__ beta, const float* __restrict__ mean,
    const float* __restrict__ var,
    const unsigned short* __restrict__ identf8, unsigned* __restrict__ hpostb, int N)
{
  const int w = threadIdx.x >> 6, l = threadIdx.x & 63;
  const int n = blockIdx.x * 4 + w;
  if (n >= N) return;
  const int e8 = l & 7;            // phase-1 edge slot (transposed)
  const int hh = l >> 3;           // head
  const int hb4 = (l & 56) << 2;   // tail bpermute base
  const int c0 = l * 2;
  const unsigned l2 = (unsigned)(l * 2);
  const float adp = ad1[(unsigned)n * 8u + (unsigned)hh];
  const int jb = starts[n], je = ends[n];

  const float bb0 = bias1[c0], bb1 = bias1[c0 + 1];
  const float sc0 = gamma[c0] * rsqrtf(var[c0] + BN_EPS);
  const float sc1 = gamma[c0 + 1] * rsqrtf(var[c0 + 1] + BN_EPS);
  const float mn0 = mean[c0], mn1 = mean[c0 + 1];
  const float bt0 = beta[c0], bt1 = beta[c0 + 1];

  const char* h1c = (const char*)h1f8;

  float dsum = 0.f;
  f32x2 acc2 = {0.f, 0.f};

#define PHASE2(K, SVEC, EW) { \
    unsigned sk = (unsigned)__builtin_amdgcn_readlane(SVEC, (K)); \
    float ewk = __uint_as_float((unsigned) \
        __builtin_amdgcn_ds_swizzle((int)__float_as_uint(EW), 0x18 | ((K) << 5))); \
    unsigned u8 = *(const unsigned short*)(h1c + ((size_t)sk << 7) + l2); \
    f32x2 hv = __builtin_amdgcn_cvt_pk_f32_fp8((int)u8, false); \
    acc2 += ewk * hv; }

  int j = jb;
  for (; j + 8 <= je; j += 8) {
    int svec = ssrc[j + e8];
    float e = as1[(unsigned)svec * 8u + (unsigned)hh] + adp;
    e = fmaxf(e, NEG_SLOPE * e);
    float ew = exp2f(e);
    dsum += ew;
    PHASE2(0, svec, ew) PHASE2(1, svec, ew) PHASE2(2, svec, ew) PHASE2(3, svec, ew)
    PHASE2(4, svec, ew) PHASE2(5, svec, ew) PHASE2(6, svec, ew) PHASE2(7, svec, ew)
  }
  int rem = je - j;
  if (rem > 0) {
    int jj = j + (e8 < rem ? e8 : 0);
    int svec = ssrc[jj];
    float e = as1[(unsigned)svec * 8u + (unsigned)hh] + adp;
    e = fmaxf(e, NEG_SLOPE * e);
    float ew = (e8 < rem) ? exp2f(e) : 0.f;
    dsum += ew;
    for (int k = 0; k < rem; ++k) {
      unsigned sk = (unsigned)__builtin_amdgcn_readlane(svec, k);
      float ewk = __uint_as_float(
          __builtin_amdgcn_ds_bpermute(hb4 + (k << 2), __float_as_uint(ew)));
      unsigned u8 = *(const unsigned short*)(h1c + ((size_t)sk << 7) + l2);
      f32x2 hv = __builtin_amdgcn_cvt_pk_f32_fp8((int)u8, false);
      acc2 += ewk * hv;
    }
  }
#undef PHASE2

  dsum += __shfl_xor(dsum, 1, 64);
  dsum += __shfl_xor(dsum, 2, 64);
  dsum += __shfl_xor(dsum, 4, 64);

  float inv = 1.f / (dsum + 1e-16f);
  unsigned uid8 = *(const unsigned short*)((const char*)identf8 + ((unsigned)n << 7) + l2);
  f32x2 idv = __builtin_amdgcn_cvt_pk_f32_fp8((int)uid8, false);
  float o0 = acc2.x * inv + bb0;
  float o1 = acc2.y * inv + bb1;
  o0 = (o0 - mn0) * sc0 + bt0;
  o1 = (o1 - mn1) * sc1 + bt1;
  o0 = o0 > 0.f ? o0 : expm1f(o0);
  o1 = o1 > 0.f ? o1 : expm1f(o1);
  o0 += idv.x; o1 += idv.y;
  hpostb[(unsigned)n * 64u + (unsigned)l] = pack2bf(o0, o1);
}

// ---------------------------------------------------------------------------
// MFMA GEMM2, LDS-free. B-frags from B2buf (incl. alpha cols 48/49).
// FP8 h2 split: h2a8 [N][8 uints] + h2b28 [N][2 uints].
// ---------------------------------------------------------------------------
__global__ __launch_bounds__(256) void gemm2_kernel(
    const unsigned* __restrict__ hpostb, const unsigned short* __restrict__ B2buf,
    unsigned* __restrict__ h2a8, unsigned* __restrict__ h2b28,
    float* __restrict__ as2, float* __restrict__ ad2, int N)
{
  const int t = threadIdx.x;
  const int l = t & 63, wave = t >> 6;
  const int lx = l & 15, ly = l >> 4;
  const int row0 = blockIdx.x * 128;

  short8 b[3][4];
  short8 b4[4];
  #pragma unroll
  for (int nf = 0; nf < 3; ++nf) {
    int c = nf * 16 + lx;
    #pragma unroll
    for (int kf = 0; kf < 4; ++kf)
      b[nf][kf] = *(const short8*)(B2buf + c * 128 + kf * 32 + ly * 8);
  }
  #pragma unroll
  for (int kf = 0; kf < 4; ++kf)
    b4[kf] = *(const short8*)(B2buf + (48 + lx) * 128 + kf * 32 + ly * 8);

  #pragma unroll
  for (int i2 = 0; i2 < 2; ++i2) {
    int mf = wave * 2 + i2;
    int arow = row0 + mf * 16 + lx;
    short8 a[4];
    #pragma unroll
    for (int kf = 0; kf < 4; ++kf) {
      U8 f;
      f.u = make_uint4(0, 0, 0, 0);
      if (arow < N)
        f.u = *(const uint4*)(hpostb + (unsigned)arow * 64u + (unsigned)(kf * 16 + ly * 4));
      a[kf] = f.s;
    }

    int rbase = row0 + mf * 16 + ly * 4;

    #pragma unroll
    for (int nf = 0; nf < 3; ++nf) {
      f32x4 acc = {0.f, 0.f, 0.f, 0.f};
      #pragma unroll
      for (int kf = 0; kf < 4; ++kf)
        acc = __builtin_amdgcn_mfma_f32_16x16x32_bf16(a[kf], b[nf][kf], acc, 0, 0, 0);
      int c = nf * 16 + lx;
      #pragma unroll
      for (int reg = 0; reg < 4; ++reg) {
        float v = acc[reg];
        float v1 = __shfl_xor(v, 1, 64);
        float v2 = __shfl_xor(v, 2, 64);
        float v3 = __shfl_xor(v1, 2, 64);
        int r = rbase + reg;
        if (r < N && c < 40 && !(lx & 3)) {
          int u = __builtin_amdgcn_cvt_pk_fp8_f32(v, v1, 0, false);
          u = __builtin_amdgcn_cvt_pk_fp8_f32(v2, v3, u, true);
          int c4 = c >> 2;
          if (c < 32) h2a8[((unsigned)r << 3) + (unsigned)c4] = (unsigned)u;
          else        h2b28[((unsigned)r << 1) + (unsigned)(c4 - 8)] = (unsigned)u;
        }
      }
    }
    {
      f32x4 acc = {0.f, 0.f, 0.f, 0.f};
      #pragma unroll
      for (int kf = 0; kf < 4; ++kf)
        acc = __builtin_amdgcn_mfma_f32_16x16x32_bf16(a[kf], b4[kf], acc, 0, 0, 0);
      #pragma unroll
      for (int reg = 0; reg < 4; ++reg) {
        int r = rbase + reg;
        if (r < N) {
          if (lx == 0) as2[r] = acc[reg];
          else if (lx == 1) ad2[r] = acc[reg];
        }
      }
    }
  }
}

// ---------------------------------------------------------------------------
// Layer-2 aggregation + bias2 + fused log_softmax. FP8 h2 gather,
// 6 edge-groups of 10 lanes, x2 unrolled; packed fp8 decode.
// ---------------------------------------------------------------------------
__global__ __launch_bounds__(256) void agg2_kernel(
    const int* __restrict__ starts, const int* __restrict__ ends,
    const int* __restrict__ ssrc,
    const float* __restrict__ as2, const float* __restrict__ ad2,
    const unsigned* __restrict__ h2a8, const unsigned* __restrict__ h2b28,
    const float* __restrict__ bias2,
    float* __restrict__ outp, int N)
{
  const int w = threadIdx.x >> 6, l = threadIdx.x & 63;
  const int n = blockIdx.x * 4 + w;
  if (n >= N) return;
  const int g = l / 10;            // 0..5 (6 for idle lanes 60-63)
  const int q = l - g * 10;        // dword index 0..9
  const bool act = l < 60;
  const float ad = ad2[n];         // prescaled
  const int jb = starts[n], je = ends[n];

  const char* hbase = (q < 8) ? ((const char*)h2a8 + (unsigned)q * 4u)
                              : ((const char*)h2b28 + (unsigned)(q - 8) * 4u);
  const unsigned hshift = (q < 8) ? 5u : 3u;
  const char* as2c = (const char*)as2;

  float dsum = 0.f;
  f32x2 acc01 = {0.f, 0.f}, acc23 = {0.f, 0.f};

#define EDGE2(JJ, GUARD) { \
    bool v_ = act && (GUARD); \
    unsigned s = v_ ? (unsigned)ssrc[JJ] : 0u; \
    float e = *(const float*)(as2c + (s << 2)) + ad; \
    e = fmaxf(e, NEG_SLOPE * e); \
    float ex = v_ ? exp2f(e) : 0.f; \
    unsigned u = *(const unsigned*)(hbase + ((size_t)s << hshift)); \
    dsum += ex; \
    f32x2 lo = __builtin_amdgcn_cvt_pk_f32_fp8((int)u, false); \
    f32x2 hi = __builtin_amdgcn_cvt_pk_f32_fp8((int)u, true); \
    acc01 += ex * lo; \
    acc23 += ex * hi; }

  int j = jb;
  for (; j + 12 <= je; j += 12) {
    EDGE2(j + g, true)
    EDGE2(j + 6 + g, true)
  }
  for (; j < je; j += 6) {
    EDGE2(j + g, (j + g) < je)
  }
#undef EDGE2

  float a0 = acc01.x, a1 = acc01.y, a2 = acc23.x, a3 = acc23.y;

#define COMB(A) { \
    float t_ = A + __shfl(A, l + 30, 64); \
    A = t_ + __shfl(t_, l + 10, 64) + __shfl(t_, l + 20, 64); }
  COMB(a0) COMB(a1) COMB(a2) COMB(a3) COMB(dsum)
#undef COMB

  float inv = 1.f / (dsum + 1e-16f);
  float o0 = a0 * inv + bias2[q * 4 + 0];
  float o1 = a1 * inv + bias2[q * 4 + 1];
  float o2 = a2 * inv + bias2[q * 4 + 2];
  float o3 = a3 * inv + bias2[q * 4 + 3];

  float m4 = fmaxf(fmaxf(o0, o1), fmaxf(o2, o3));
  float mx = wave_max64(l < 10 ? m4 : -3.4e38f);
  float se = wave_sum64(l < 10 ? __expf(o0 - mx) + __expf(o1 - mx) +
                                 __expf(o2 - mx) + __expf(o3 - mx) : 0.f);
  float ls = logf(se);
  if (l < 10)
    *(float4*)&outp[(size_t)n * 40 + q * 4] =
        make_float4(o0 - mx - ls, o1 - mx - ls, o2 - mx - ls, o3 - mx - ls);
}

// ---------------------------------------------------------------------------
extern "C" void kernel_launch(void* const* d_in, const int* in_sizes, int n_in,
                              void* d_out, int out_size, void* d_ws, size_t ws_size,
                              hipStream_t stream)
{
  const float* x        = (const float*)d_in[0];
  const int*   ei       = (const int*)d_in[1];
  const float* W1       = (const float*)d_in[2];
  const float* att_src1 = (const float*)d_in[3];
  const float* att_dst1 = (const float*)d_in[4];
  const float* bias1    = (const float*)d_in[5];
  const float* bn_gamma = (const float*)d_in[6];
  const float* bn_beta  = (const float*)d_in[7];
  const float* bn_mean  = (const float*)d_in[8];
  const float* bn_var   = (const float*)d_in[9];
  const float* W2       = (const float*)d_in[10];
  const float* att_src2 = (const float*)d_in[11];
  const float* att_dst2 = (const float*)d_in[12];
  const float* bias2    = (const float*)d_in[13];
  const float* W_skip   = (const float*)d_in[14];
  const float* b_skip   = (const float*)d_in[15];

  const int N = in_sizes[0] / 128;
  const int E = in_sizes[1] / 2;
  const int T = E + N;
  const int NB = (N + BMASK) >> BSH;   // 196

  char* p = (char*)d_ws;
  auto alloc = [&](size_t bytes) { char* q = p; p += (bytes + 255) & ~255ull; return q; };
  unsigned short* h1f8   = (unsigned short*)alloc((size_t)N * 128);  // fp8 [N][128]
  unsigned short* identf8= (unsigned short*)alloc((size_t)N * 128);  // fp8 [N][128]
  unsigned* hpostb = (unsigned*)alloc((size_t)N * 64 * 4);           // bf16 [N][128]
  float* as1     = (float*)alloc((size_t)N * 8 * 4);
  float* ad1     = (float*)alloc((size_t)N * 8 * 4);
  unsigned short* Bbuf   = (unsigned short*)alloc(256 * 128 * 2);
  unsigned short* Mextbuf= (unsigned short*)alloc(16 * 128 * 2);
  unsigned short* B2buf  = (unsigned short*)alloc(64 * 128 * 2);
  int*   starts  = (int*)alloc((size_t)N * 4);
  int*   ends    = (int*)alloc((size_t)N * 4);
  unsigned* pkbuf= (unsigned*)alloc((size_t)NB * BCAP * 4);
  int*   ssrc    = (int*)alloc((size_t)NB * BCAP * 4);
  int*   bcur    = (int*)alloc((size_t)NB * 4);
  // layer-2 reuse of dead layer-1 buffers (h1f8/as1/ad1 dead after agg1)
  unsigned* h2a8  = (unsigned*)h1f8;                          // [N][8] uints
  unsigned* h2b28 = (unsigned*)((char*)h1f8 + (size_t)N * 32); // [N][2] uints
  float* as2 = as1;
  float* ad2 = ad1;

  const int* ei_src = ei;
  const int* ei_dst = ei + E;

  prep_kernel<<<4, 256, 0, stream>>>(W1, W_skip, att_src1, att_dst1,
                                     W2, att_src2, att_dst2,
                                     Bbuf, Mextbuf, B2buf, bcur, NB);

  const int G1 = (N + 127) / 128;
  int NBLK_A = (T + CH_MAX - 1) / CH_MAX;
  if (NBLK_A < 512) NBLK_A = 512;
  const int chunk = (T + NBLK_A - 1) / NBLK_A;
  gemm1_scatter_kernel<<<G1 + NBLK_A, 256, 0, stream>>>(
      x, Bbuf, Mextbuf, b_skip, h1f8, identf8, as1, ad1, N,
      ei_src, ei_dst, bcur, pkbuf, E, T, chunk, NB, G1);

  passB_kernel<<<NB, 256, 0, stream>>>(pkbuf, bcur, starts, ends, ssrc, N);

  agg1_kernel<<<(N + 3) / 4, 256, 0, stream>>>(starts, ends, ssrc, as1, ad1, h1f8,
                                               bias1, bn_gamma, bn_beta, bn_mean, bn_var,
                                               identf8, hpostb, N);
  gemm2_kernel<<<(N + 127) / 128, 256, 0, stream>>>(hpostb, B2buf,
                                                    h2a8, h2b28, as2, ad2, N);
  agg2_kernel<<<(N + 3) / 4, 256, 0, stream>>>(starts, ends, ssrc, as2, ad2,
                                               h2a8, h2b28, bias2,
                                               (float*)d_out, N);
}

// Round 17
// 222.145 us; speedup vs baseline: 1.1692x; 1.0012x over previous
//
#include <hip/hip_runtime.h>
#include <math.h>

#define NEG_SLOPE 0.2f
#define BN_EPS 1e-5f
#define BSH 9
#define BMASK 511
#define LOG2E 1.44269504088896f
#define BCAP 12288
#define CH_MAX 3400

typedef __attribute__((ext_vector_type(8))) short short8;
typedef __attribute__((ext_vector_type(4))) float f32x4;
typedef __attribute__((ext_vector_type(2))) float f32x2;

__device__ __forceinline__ float wave_max64(float v) {
  #pragma unroll
  for (int o = 32; o; o >>= 1) v = fmaxf(v, __shfl_xor(v, o, 64));
  return v;
}
__device__ __forceinline__ float wave_sum64(float v) {
  #pragma unroll
  for (int o = 32; o; o >>= 1) v += __shfl_xor(v, o, 64);
  return v;
}

__device__ __forceinline__ unsigned pack2bf(float a, float b) {
  unsigned ua = __float_as_uint(a);
  unsigned ub = __float_as_uint(b);
  ua = ua + 0x7fffu + ((ua >> 16) & 1u);
  ub = ub + 0x7fffu + ((ub >> 16) & 1u);
  return (ua >> 16) | (ub & 0xffff0000u);
}
__device__ __forceinline__ float bf_lo(unsigned u) { return __uint_as_float(u << 16); }
__device__ __forceinline__ float bf_hi(unsigned u) { return __uint_as_float(u & 0xffff0000u); }

union U8 { short8 s; uint4 u; };

// ---------------------------------------------------------------------------
// prep (4 blocks x 256): bf16 fragment-layout weight buffers + bcur zero.
// ---------------------------------------------------------------------------
__global__ __launch_bounds__(256) void prep_kernel(
    const float* __restrict__ W1, const float* __restrict__ Wsk,
    const float* __restrict__ att_s, const float* __restrict__ att_d,
    const float* __restrict__ W2,
    const float* __restrict__ att_s2, const float* __restrict__ att_d2,
    unsigned short* __restrict__ Bbuf, unsigned short* __restrict__ Mextbuf,
    unsigned short* __restrict__ B2buf,
    int* __restrict__ bcur, int NB)
{
  const int t = threadIdx.x;
  const int bid = blockIdx.x;

  if (bid == 0) {
    __shared__ float Ms[128][16];
    __shared__ float M2s[128][2];
    if (t < NB) bcur[t] = 0;
    if (t < 128) {
      int k = t;
      #pragma unroll
      for (int h = 0; h < 8; ++h) {
        float s = 0.f, d = 0.f;
        #pragma unroll
        for (int c = 0; c < 16; ++c) {
          float w = W1[k * 128 + h * 16 + c];
          s += w * att_s[h * 16 + c];
          d += w * att_d[h * 16 + c];
        }
        Ms[k][h] = s * LOG2E;
        Ms[k][8 + h] = d * LOG2E;
      }
      float s2 = 0.f, d2 = 0.f;
      #pragma unroll
      for (int c = 0; c < 40; ++c) {
        float w = W2[k * 40 + c];
        s2 += w * att_s2[c];
        d2 += w * att_d2[c];
      }
      M2s[k][0] = s2 * LOG2E;
      M2s[k][1] = d2 * LOG2E;
    }
    __syncthreads();
    unsigned* Mu = (unsigned*)Mextbuf;
    for (int idx = t; idx < 16 * 64; idx += 256) {
      int h = idx >> 6, u = idx & 63;
      Mu[h * 64 + u] = pack2bf(Ms[2 * u][h], Ms[2 * u + 1][h]);
    }
    unsigned* B2u = (unsigned*)B2buf;
    for (int idx = t; idx < 2 * 64; idx += 256) {
      int cc = idx >> 6, u = idx & 63;
      B2u[(48 + cc) * 64 + u] = pack2bf(M2s[2 * u][cc], M2s[2 * u + 1][cc]);
    }
  } else if (bid <= 2) {
    int c = (bid - 1) * 128 + (t >> 1);
    int half = t & 1;
    const float* src = (c < 128) ? (W1 + c) : (Wsk + (c - 128));
    unsigned* out = (unsigned*)Bbuf + c * 64 + half * 32;
    #pragma unroll 8
    for (int u = 0; u < 32; ++u) {
      int k = half * 64 + 2 * u;
      out[u] = pack2bf(src[(size_t)k * 128], src[(size_t)(k + 1) * 128]);
    }
  } else {
    unsigned* B2u = (unsigned*)B2buf;
    for (int idx = t; idx < 40 * 64; idx += 256) {
      int c = idx >> 6, u = idx & 63;
      B2u[c * 64 + u] = pack2bf(W2[(2 * u) * 40 + c], W2[(2 * u + 1) * 40 + c]);
    }
    for (int idx = t; idx < 22 * 64; idx += 256) {
      int zc = idx >> 6, u = idx & 63;
      int c = (zc < 8) ? (40 + zc) : (50 + (zc - 8));
      B2u[c * 64 + u] = 0;
    }
  }
}

// ---------------------------------------------------------------------------
// FUSED gemm1 + scatterA (single-pass scatter via LDS staging).
// ---------------------------------------------------------------------------
__global__ __launch_bounds__(256) void gemm1_scatter_kernel(
    const float* __restrict__ X,
    const unsigned short* __restrict__ Bbuf,
    const unsigned short* __restrict__ Mextbuf,
    const float* __restrict__ bsk,
    unsigned short* __restrict__ h1f8, unsigned short* __restrict__ identf8,
    float* __restrict__ alpha_s, float* __restrict__ alpha_d, int N,
    const int* __restrict__ esrc, const int* __restrict__ edst,
    int* __restrict__ bcur, unsigned* __restrict__ pkbuf,
    int E, int T, int chunk, int NB, int G1)
{
  __shared__ uint4 Asm4[2048];           // 32 KB (gemm1 tile / scatter scratch)
  const int t = threadIdx.x;

  if ((int)blockIdx.x >= G1) {
    int* hist  = (int*)Asm4;
    int* lbase = hist + 256;
    int* lcur  = hist + 512;
    unsigned* spk = (unsigned*)(hist + 768);
    unsigned char* sbk = (unsigned char*)(spk + CH_MAX);
    const int bid = (int)blockIdx.x - G1;
    hist[t] = 0;
    __syncthreads();
    int s0 = bid * chunk;
    int s1 = min(s0 + chunk, T);
    for (int i = s0 + t; i < s1; i += 256) {
      int d, s;
      if (i < E) { d = edst[i]; s = esrc[i]; } else { d = s = i - E; }
      int b = d >> BSH;
      int li = i - s0;
      spk[li] = ((unsigned)(d & BMASK) << 17) | (unsigned)s;
      sbk[li] = (unsigned char)b;
      atomicAdd(&hist[b], 1);
    }
    __syncthreads();
    if (t < NB) {
      int h = hist[t];
      lbase[t] = t * BCAP + (h ? atomicAdd(&bcur[t], h) : 0);
      lcur[t] = 0;
    }
    __syncthreads();
    const int cnt2 = s1 - s0;
    for (int li = t; li < cnt2; li += 256) {
      int b = sbk[li];
      int p = lbase[b] + atomicAdd(&lcur[b], 1);
      pkbuf[p] = spk[li];
    }
    return;
  }

  // -------------------- gemm1 path --------------------
  const int l = t & 63, wave = t >> 6;
  const int lx = l & 15, ly = l >> 4;
  const int row0 = blockIdx.x * 128;
  const int wn0 = wave * 64;

  short8 b[4][4];
  short8 b4[4] = {};
  #pragma unroll
  for (int nf = 0; nf < 4; ++nf) {
    int c = wn0 + nf * 16 + lx;
    #pragma unroll
    for (int kf = 0; kf < 4; ++kf)
      b[nf][kf] = *(const short8*)(Bbuf + c * 128 + kf * 32 + ly * 8);
  }
  if (wave == 0) {
    #pragma unroll
    for (int kf = 0; kf < 4; ++kf)
      b4[kf] = *(const short8*)(Mextbuf + lx * 128 + kf * 32 + ly * 8);
  }

  {
    int rl = t >> 1;
    int half = t & 1;
    int r = row0 + rl;
    const float* xp = X + (size_t)r * 128 + half * 64;
    #pragma unroll
    for (int i = 0; i < 8; ++i) {
      float4 f0 = make_float4(0.f, 0.f, 0.f, 0.f), f1 = f0;
      if (r < N) {
        f0 = *(const float4*)(xp + i * 8);
        f1 = *(const float4*)(xp + i * 8 + 4);
      }
      uint4 u;
      u.x = pack2bf(f0.x, f0.y); u.y = pack2bf(f0.z, f0.w);
      u.z = pack2bf(f1.x, f1.y); u.w = pack2bf(f1.z, f1.w);
      int woff = (rl * 256 + half * 128 + i * 16) ^ ((rl & 7) << 4);
      *(uint4*)((char*)Asm4 + woff) = u;
    }
  }
  __syncthreads();

  float bval[4];
  if (wave >= 2) {
    #pragma unroll
    for (int nf = 0; nf < 4; ++nf) bval[nf] = bsk[(wave - 2) * 64 + nf * 16 + lx];
  }

  for (int mf = 0; mf < 8; ++mf) {
    short8 a[4];
    int rowl = mf * 16 + lx;
    #pragma unroll
    for (int kf = 0; kf < 4; ++kf)
      a[kf] = *(short8*)((char*)Asm4 + ((rowl * 256 + kf * 64 + ly * 16) ^ ((lx & 7) << 4)));

    int rbase = row0 + mf * 16 + ly * 4;

    #pragma unroll
    for (int nf = 0; nf < 4; ++nf) {
      f32x4 acc = {0.f, 0.f, 0.f, 0.f};
      #pragma unroll
      for (int kf = 0; kf < 4; ++kf)
        acc = __builtin_amdgcn_mfma_f32_16x16x32_bf16(a[kf], b[nf][kf], acc, 0, 0, 0);
      if (wave < 2) {
        int c = wn0 + nf * 16 + lx;
        #pragma unroll
        for (int reg = 0; reg < 4; ++reg) {
          float v = acc[reg];
          float vp = __shfl_xor(v, 1, 64);
          int r = rbase + reg;
          if (!(lx & 1) && r < N) {
            int u = __builtin_amdgcn_cvt_pk_fp8_f32(v, vp, 0, false);
            *(unsigned short*)((char*)h1f8 + (unsigned)r * 128u + (unsigned)c) =
                (unsigned short)u;
          }
        }
      } else {
        int c = (wave - 2) * 64 + nf * 16 + lx;
        #pragma unroll
        for (int reg = 0; reg < 4; ++reg) {
          float v = acc[reg] + bval[nf];
          float vp = __shfl_xor(v, 1, 64);
          int r = rbase + reg;
          if (!(lx & 1) && r < N) {
            int u = __builtin_amdgcn_cvt_pk_fp8_f32(v, vp, 0, false);
            *(unsigned short*)((char*)identf8 + (unsigned)r * 128u + (unsigned)c) =
                (unsigned short)u;
          }
        }
      }
    }

    if (wave == 0) {
      f32x4 acc = {0.f, 0.f, 0.f, 0.f};
      #pragma unroll
      for (int kf = 0; kf < 4; ++kf)
        acc = __builtin_amdgcn_mfma_f32_16x16x32_bf16(a[kf], b4[kf], acc, 0, 0, 0);
      #pragma unroll
      for (int reg = 0; reg < 4; ++reg) {
        int r = rbase + reg;
        if (r < N) {
          if (lx < 8) alpha_s[(size_t)r * 8 + lx] = acc[reg];
          else        alpha_d[(size_t)r * 8 + (lx - 8)] = acc[reg];
        }
      }
    }
  }
}

// ---------------------------------------------------------------------------
// passB: one block per bucket.
// ---------------------------------------------------------------------------
__global__ __launch_bounds__(256) void passB_kernel(
    const unsigned* __restrict__ pkbuf, const int* __restrict__ bcnt,
    int* __restrict__ starts, int* __restrict__ ends,
    int* __restrict__ ssrc, int N)
{
  __shared__ int cnt[512];
  __shared__ int ps[256];
  __shared__ int cur[512];
  const int t = threadIdx.x;
  const int b = blockIdx.x;
  const int bs = b * BCAP;
  const int be = bs + bcnt[b];

  cnt[t] = 0; cnt[t + 256] = 0;
  __syncthreads();
  for (int i = bs + t; i < be; i += 256)
    atomicAdd(&cnt[pkbuf[i] >> 17], 1);
  __syncthreads();

  int a = cnt[2 * t], b2 = cnt[2 * t + 1];
  ps[t] = a + b2;
  __syncthreads();
  for (int d = 1; d < 256; d <<= 1) {
    int u = (t >= d) ? ps[t - d] : 0;
    __syncthreads();
    ps[t] += u;
    __syncthreads();
  }
  int excl = ps[t] - (a + b2);
  cur[2 * t] = excl;
  cur[2 * t + 1] = excl + a;
  __syncthreads();

  const int node0 = b << BSH;
  {
    int n0 = node0 + 2 * t, n1 = node0 + 2 * t + 1;
    if (n0 < N) { starts[n0] = bs + cur[2 * t];     ends[n0] = bs + cur[2 * t] + a; }
    if (n1 < N) { starts[n1] = bs + cur[2 * t + 1]; ends[n1] = bs + cur[2 * t + 1] + b2; }
  }
  __syncthreads();

  for (int i = bs + t; i < be; i += 256) {
    unsigned pk = pkbuf[i];
    int d = pk >> 17;
    int p = atomicAdd(&cur[d], 1);
    ssrc[bs + p] = (int)(pk & 0x1FFFFu);
  }
}

// ---------------------------------------------------------------------------
// Layer-1 aggregation, two-phase (transposed phase-1) with software
// prefetch: next block's ssrc + as1 loads are issued BEFORE the current
// block's 8 gathers, so their latency hides under the in-flight gathers.
// ---------------------------------------------------------------------------
__global__ __launch_bounds__(256) void agg1_kernel(
    const int* __restrict__ starts, const int* __restrict__ ends,
    const int* __restrict__ ssrc,
    const float* __restrict__ as1, const float* __restrict__ ad1,
    const unsigned short* __restrict__ h1f8,
    const float* __restrict__ bias1, const float* __restrict__ gamma,
    const float* __restrict__ beta, const float* __restrict__ mean,
    const float* __restrict__ var,
    const unsigned short* __restrict__ identf8, unsigned* __restrict__ hpostb, int N)
{
  const int w = threadIdx.x >> 6, l = threadIdx.x & 63;
  const int n = blockIdx.x * 4 + w;
  if (n >= N) return;
  const int e8 = l & 7;            // phase-1 edge slot (transposed)
  const int hh = l >> 3;           // head
  const int hb4 = (l & 56) << 2;   // tail bpermute base
  const int c0 = l * 2;
  const unsigned l2 = (unsigned)(l * 2);
  const float adp = ad1[(unsigned)n * 8u + (unsigned)hh];
  const int jb = starts[n], je = ends[n];

  const float bb0 = bias1[c0], bb1 = bias1[c0 + 1];
  const float sc0 = gamma[c0] * rsqrtf(var[c0] + BN_EPS);
  const float sc1 = gamma[c0 + 1] * rsqrtf(var[c0 + 1] + BN_EPS);
  const float mn0 = mean[c0], mn1 = mean[c0 + 1];
  const float bt0 = beta[c0], bt1 = beta[c0 + 1];

  const char* h1c = (const char*)h1f8;

  float dsum = 0.f;
  f32x2 acc2 = {0.f, 0.f};

#define PHASE2(K, SVEC, EW) { \
    unsigned sk = (unsigned)__builtin_amdgcn_readlane(SVEC, (K)); \
    float ewk = __uint_as_float((unsigned) \
        __builtin_amdgcn_ds_swizzle((int)__float_as_uint(EW), 0x18 | ((K) << 5))); \
    unsigned u8 = *(const unsigned short*)(h1c + ((size_t)sk << 7) + l2); \
    f32x2 hv = __builtin_amdgcn_cvt_pk_f32_fp8((int)u8, false); \
    acc2 += ewk * hv; }

  int j = jb;
  if (j + 8 <= je) {
    int svec = ssrc[j + e8];
    float asv = as1[(unsigned)svec * 8u + (unsigned)hh];
    for (; j + 8 <= je; j += 8) {
      // prefetch next block (overlaps the 8 gathers below)
      int svec_n = 0;
      float asv_n = 0.f;
      if (j + 16 <= je) {
        svec_n = ssrc[j + 8 + e8];
        asv_n = as1[(unsigned)svec_n * 8u + (unsigned)hh];
      }
      float e = asv + adp;
      e = fmaxf(e, NEG_SLOPE * e);
      float ew = exp2f(e);
      dsum += ew;
      PHASE2(0, svec, ew) PHASE2(1, svec, ew) PHASE2(2, svec, ew) PHASE2(3, svec, ew)
      PHASE2(4, svec, ew) PHASE2(5, svec, ew) PHASE2(6, svec, ew) PHASE2(7, svec, ew)
      svec = svec_n;
      asv = asv_n;
    }
  }
  int rem = je - j;
  if (rem > 0) {
    int jj = j + (e8 < rem ? e8 : 0);
    int svec = ssrc[jj];
    float e = as1[(unsigned)svec * 8u + (unsigned)hh] + adp;
    e = fmaxf(e, NEG_SLOPE * e);
    float ew = (e8 < rem) ? exp2f(e) : 0.f;
    dsum += ew;
    for (int k = 0; k < rem; ++k) {
      unsigned sk = (unsigned)__builtin_amdgcn_readlane(svec, k);
      float ewk = __uint_as_float(
          __builtin_amdgcn_ds_bpermute(hb4 + (k << 2), __float_as_uint(ew)));
      unsigned u8 = *(const unsigned short*)(h1c + ((size_t)sk << 7) + l2);
      f32x2 hv = __builtin_amdgcn_cvt_pk_f32_fp8((int)u8, false);
      acc2 += ewk * hv;
    }
  }
#undef PHASE2

  dsum += __shfl_xor(dsum, 1, 64);
  dsum += __shfl_xor(dsum, 2, 64);
  dsum += __shfl_xor(dsum, 4, 64);

  float inv = 1.f / (dsum + 1e-16f);
  unsigned uid8 = *(const unsigned short*)((const char*)identf8 + ((unsigned)n << 7) + l2);
  f32x2 idv = __builtin_amdgcn_cvt_pk_f32_fp8((int)uid8, false);
  float o0 = acc2.x * inv + bb0;
  float o1 = acc2.y * inv + bb1;
  o0 = (o0 - mn0) * sc0 + bt0;
  o1 = (o1 - mn1) * sc1 + bt1;
  o0 = o0 > 0.f ? o0 : expm1f(o0);
  o1 = o1 > 0.f ? o1 : expm1f(o1);
  o0 += idv.x; o1 += idv.y;
  hpostb[(unsigned)n * 64u + (unsigned)l] = pack2bf(o0, o1);
}

// ---------------------------------------------------------------------------
// MFMA GEMM2, LDS-free. B-frags from B2buf (incl. alpha cols 48/49).
// FP8 h2 split: h2a8 [N][8 uints] + h2b28 [N][2 uints].
// ---------------------------------------------------------------------------
__global__ __launch_bounds__(256) void gemm2_kernel(
    const unsigned* __restrict__ hpostb, const unsigned short* __restrict__ B2buf,
    unsigned* __restrict__ h2a8, unsigned* __restrict__ h2b28,
    float* __restrict__ as2, float* __restrict__ ad2, int N)
{
  const int t = threadIdx.x;
  const int l = t & 63, wave = t >> 6;
  const int lx = l & 15, ly = l >> 4;
  const int row0 = blockIdx.x * 128;

  short8 b[3][4];
  short8 b4[4];
  #pragma unroll
  for (int nf = 0; nf < 3; ++nf) {
    int c = nf * 16 + lx;
    #pragma unroll
    for (int kf = 0; kf < 4; ++kf)
      b[nf][kf] = *(const short8*)(B2buf + c * 128 + kf * 32 + ly * 8);
  }
  #pragma unroll
  for (int kf = 0; kf < 4; ++kf)
    b4[kf] = *(const short8*)(B2buf + (48 + lx) * 128 + kf * 32 + ly * 8);

  #pragma unroll
  for (int i2 = 0; i2 < 2; ++i2) {
    int mf = wave * 2 + i2;
    int arow = row0 + mf * 16 + lx;
    short8 a[4];
    #pragma unroll
    for (int kf = 0; kf < 4; ++kf) {
      U8 f;
      f.u = make_uint4(0, 0, 0, 0);
      if (arow < N)
        f.u = *(const uint4*)(hpostb + (unsigned)arow * 64u + (unsigned)(kf * 16 + ly * 4));
      a[kf] = f.s;
    }

    int rbase = row0 + mf * 16 + ly * 4;

    #pragma unroll
    for (int nf = 0; nf < 3; ++nf) {
      f32x4 acc = {0.f, 0.f, 0.f, 0.f};
      #pragma unroll
      for (int kf = 0; kf < 4; ++kf)
        acc = __builtin_amdgcn_mfma_f32_16x16x32_bf16(a[kf], b[nf][kf], acc, 0, 0, 0);
      int c = nf * 16 + lx;
      #pragma unroll
      for (int reg = 0; reg < 4; ++reg) {
        float v = acc[reg];
        float v1 = __shfl_xor(v, 1, 64);
        float v2 = __shfl_xor(v, 2, 64);
        float v3 = __shfl_xor(v1, 2, 64);
        int r = rbase + reg;
        if (r < N && c < 40 && !(lx & 3)) {
          int u = __builtin_amdgcn_cvt_pk_fp8_f32(v, v1, 0, false);
          u = __builtin_amdgcn_cvt_pk_fp8_f32(v2, v3, u, true);
          int c4 = c >> 2;
          if (c < 32) h2a8[((unsigned)r << 3) + (unsigned)c4] = (unsigned)u;
          else        h2b28[((unsigned)r << 1) + (unsigned)(c4 - 8)] = (unsigned)u;
        }
      }
    }
    {
      f32x4 acc = {0.f, 0.f, 0.f, 0.f};
      #pragma unroll
      for (int kf = 0; kf < 4; ++kf)
        acc = __builtin_amdgcn_mfma_f32_16x16x32_bf16(a[kf], b4[kf], acc, 0, 0, 0);
      #pragma unroll
      for (int reg = 0; reg < 4; ++reg) {
        int r = rbase + reg;
        if (r < N) {
          if (lx == 0) as2[r] = acc[reg];
          else if (lx == 1) ad2[r] = acc[reg];
        }
      }
    }
  }
}

// ---------------------------------------------------------------------------
// Layer-2 aggregation + bias2 + fused log_softmax. FP8 h2 gather,
// 6 edge-groups of 10 lanes, x2 unrolled; packed fp8 decode.
// ---------------------------------------------------------------------------
__global__ __launch_bounds__(256) void agg2_kernel(
    const int* __restrict__ starts, const int* __restrict__ ends,
    const int* __restrict__ ssrc,
    const float* __restrict__ as2, const float* __restrict__ ad2,
    const unsigned* __restrict__ h2a8, const unsigned* __restrict__ h2b28,
    const float* __restrict__ bias2,
    float* __restrict__ outp, int N)
{
  const int w = threadIdx.x >> 6, l = threadIdx.x & 63;
  const int n = blockIdx.x * 4 + w;
  if (n >= N) return;
  const int g = l / 10;            // 0..5 (6 for idle lanes 60-63)
  const int q = l - g * 10;        // dword index 0..9
  const bool act = l < 60;
  const float ad = ad2[n];         // prescaled
  const int jb = starts[n], je = ends[n];

  const char* hbase = (q < 8) ? ((const char*)h2a8 + (unsigned)q * 4u)
                              : ((const char*)h2b28 + (unsigned)(q - 8) * 4u);
  const unsigned hshift = (q < 8) ? 5u : 3u;
  const char* as2c = (const char*)as2;

  float dsum = 0.f;
  f32x2 acc01 = {0.f, 0.f}, acc23 = {0.f, 0.f};

#define EDGE2(JJ, GUARD) { \
    bool v_ = act && (GUARD); \
    unsigned s = v_ ? (unsigned)ssrc[JJ] : 0u; \
    float e = *(const float*)(as2c + (s << 2)) + ad; \
    e = fmaxf(e, NEG_SLOPE * e); \
    float ex = v_ ? exp2f(e) : 0.f; \
    unsigned u = *(const unsigned*)(hbase + ((size_t)s << hshift)); \
    dsum += ex; \
    f32x2 lo = __builtin_amdgcn_cvt_pk_f32_fp8((int)u, false); \
    f32x2 hi = __builtin_amdgcn_cvt_pk_f32_fp8((int)u, true); \
    acc01 += ex * lo; \
    acc23 += ex * hi; }

  int j = jb;
  for (; j + 12 <= je; j += 12) {
    EDGE2(j + g, true)
    EDGE2(j + 6 + g, true)
  }
  for (; j < je; j += 6) {
    EDGE2(j + g, (j + g) < je)
  }
#undef EDGE2

  float a0 = acc01.x, a1 = acc01.y, a2 = acc23.x, a3 = acc23.y;

#define COMB(A) { \
    float t_ = A + __shfl(A, l + 30, 64); \
    A = t_ + __shfl(t_, l + 10, 64) + __shfl(t_, l + 20, 64); }
  COMB(a0) COMB(a1) COMB(a2) COMB(a3) COMB(dsum)
#undef COMB

  float inv = 1.f / (dsum + 1e-16f);
  float o0 = a0 * inv + bias2[q * 4 + 0];
  float o1 = a1 * inv + bias2[q * 4 + 1];
  float o2 = a2 * inv + bias2[q * 4 + 2];
  float o3 = a3 * inv + bias2[q * 4 + 3];

  float m4 = fmaxf(fmaxf(o0, o1), fmaxf(o2, o3));
  float mx = wave_max64(l < 10 ? m4 : -3.4e38f);
  float se = wave_sum64(l < 10 ? __expf(o0 - mx) + __expf(o1 - mx) +
                                 __expf(o2 - mx) + __expf(o3 - mx) : 0.f);
  float ls = logf(se);
  if (l < 10)
    *(float4*)&outp[(size_t)n * 40 + q * 4] =
        make_float4(o0 - mx - ls, o1 - mx - ls, o2 - mx - ls, o3 - mx - ls);
}

// ---------------------------------------------------------------------------
extern "C" void kernel_launch(void* const* d_in, const int* in_sizes, int n_in,
                              void* d_out, int out_size, void* d_ws, size_t ws_size,
                              hipStream_t stream)
{
  const float* x        = (const float*)d_in[0];
  const int*   ei       = (const int*)d_in[1];
  const float* W1       = (const float*)d_in[2];
  const float* att_src1 = (const float*)d_in[3];
  const float* att_dst1 = (const float*)d_in[4];
  const float* bias1    = (const float*)d_in[5];
  const float* bn_gamma = (const float*)d_in[6];
  const float* bn_beta  = (const float*)d_in[7];
  const float* bn_mean  = (const float*)d_in[8];
  const float* bn_var   = (const float*)d_in[9];
  const float* W2       = (const float*)d_in[10];
  const float* att_src2 = (const float*)d_in[11];
  const float* att_dst2 = (const float*)d_in[12];
  const float* bias2    = (const float*)d_in[13];
  const float* W_skip   = (const float*)d_in[14];
  const float* b_skip   = (const float*)d_in[15];

  const int N = in_sizes[0] / 128;
  const int E = in_sizes[1] / 2;
  const int T = E + N;
  const int NB = (N + BMASK) >> BSH;   // 196

  char* p = (char*)d_ws;
  auto alloc = [&](size_t bytes) { char* q = p; p += (bytes + 255) & ~255ull; return q; };
  unsigned short* h1f8   = (unsigned short*)alloc((size_t)N * 128);  // fp8 [N][128]
  unsigned short* identf8= (unsigned short*)alloc((size_t)N * 128);  // fp8 [N][128]
  unsigned* hpostb = (unsigned*)alloc((size_t)N * 64 * 4);           // bf16 [N][128]
  float* as1     = (float*)alloc((size_t)N * 8 * 4);
  float* ad1     = (float*)alloc((size_t)N * 8 * 4);
  unsigned short* Bbuf   = (unsigned short*)alloc(256 * 128 * 2);
  unsigned short* Mextbuf= (unsigned short*)alloc(16 * 128 * 2);
  unsigned short* B2buf  = (unsigned short*)alloc(64 * 128 * 2);
  int*   starts  = (int*)alloc((size_t)N * 4);
  int*   ends    = (int*)alloc((size_t)N * 4);
  unsigned* pkbuf= (unsigned*)alloc((size_t)NB * BCAP * 4);
  int*   ssrc    = (int*)alloc((size_t)NB * BCAP * 4);
  int*   bcur    = (int*)alloc((size_t)NB * 4);
  // layer-2 reuse of dead layer-1 buffers (h1f8/as1/ad1 dead after agg1)
  unsigned* h2a8  = (unsigned*)h1f8;                          // [N][8] uints
  unsigned* h2b28 = (unsigned*)((char*)h1f8 + (size_t)N * 32); // [N][2] uints
  float* as2 = as1;
  float* ad2 = ad1;

  const int* ei_src = ei;
  const int* ei_dst = ei + E;

  prep_kernel<<<4, 256, 0, stream>>>(W1, W_skip, att_src1, att_dst1,
                                     W2, att_src2, att_dst2,
                                     Bbuf, Mextbuf, B2buf, bcur, NB);

  const int G1 = (N + 127) / 128;
  int NBLK_A = (T + CH_MAX - 1) / CH_MAX;
  if (NBLK_A < 512) NBLK_A = 512;
  const int chunk = (T + NBLK_A - 1) / NBLK_A;
  gemm1_scatter_kernel<<<G1 + NBLK_A, 256, 0, stream>>>(
      x, Bbuf, Mextbuf, b_skip, h1f8, identf8, as1, ad1, N,
      ei_src, ei_dst, bcur, pkbuf, E, T, chunk, NB, G1);

  passB_kernel<<<NB, 256, 0, stream>>>(pkbuf, bcur, starts, ends, ssrc, N);

  agg1_kernel<<<(N + 3) / 4, 256, 0, stream>>>(starts, ends, ssrc, as1, ad1, h1f8,
                                               bias1, bn_gamma, bn_beta, bn_mean, bn_var,
                                               identf8, hpostb, N);
  gemm2_kernel<<<(N + 127) / 128, 256, 0, stream>>>(hpostb, B2buf,
                                                    h2a8, h2b28, as2, ad2, N);
  agg2_kernel<<<(N + 3) / 4, 256, 0, stream>>>(starts, ends, ssrc, as2, ad2,
                                               h2a8, h2b28, bias2,
                                               (float*)d_out, N);
}